// Round 3
// baseline (1133.523 us; speedup 1.0000x reference)
//
#include <hip/hip_runtime.h>
#include <math.h>

#define B_    2
#define C_    1024
#define N_    80
#define D_    3074
#define DFF_  2048
#define OD_   1026      // C+2
#define QKV_  9222      // 3*D
#define M_    160       // B*N token rows
#define EPS_  1e-5f
#define KPD_  3104      // D_ rounded up to multiple of 32 (bf16 row stride)

// split-K factors (chosen so ceil(nch/S)*(S-1) < nch -> no empty splits)
#define SQKV 6    // nch=97, per=17
#define SOP  14   // nch=97, per=7
#define SFF1 14   // nch=97, per=7
#define SFF2 16   // nch=64, per=4
#define SHD  14   // nch=97, per=7

typedef __attribute__((ext_vector_type(8))) short bf16x8;   // 8 bf16 = 4 VGPRs
typedef __attribute__((ext_vector_type(4))) float f32x4;

// fp32 -> bf16 (round-to-nearest-even), bit pattern as short
__device__ inline short f2bf(float f) {
    unsigned u = __float_as_uint(f);
    u += 0x7fffu + ((u >> 16) & 1u);
    return (short)(u >> 16);
}

// ---------------------------------------------------------------- reductions
__device__ inline float wave_sum(float v) {
#pragma unroll
    for (int off = 32; off > 0; off >>= 1) v += __shfl_down(v, off, 64);
    return v;
}

__device__ inline float wave_max(float v) {
#pragma unroll
    for (int off = 32; off > 0; off >>= 1) v = fmaxf(v, __shfl_down(v, off, 64));
    return v;
}

__device__ inline void block_reduce_2(float& s, float& s2, float* red) {
    int tid = threadIdx.x;
    int lane = tid & 63, wid = tid >> 6;
    s = wave_sum(s);
    s2 = wave_sum(s2);
    if (lane == 0) { red[wid] = s; red[4 + wid] = s2; }
    __syncthreads();
    if (tid == 0) {
        red[8] = red[0] + red[1] + red[2] + red[3];
        red[9] = red[4] + red[5] + red[6] + red[7];
    }
    __syncthreads();
    s = red[8]; s2 = red[9];
}

// ---------------------------------------------------------------- bilinear
__device__ inline void bilin_setup(int p, int& i0, int& i1, float& t) {
    float s = (p + 0.5f) * 0.0625f - 0.5f;
    s = fminf(fmaxf(s, 0.0f), 13.0f);
    i0 = (int)s;
    t = s - (float)i0;
    i1 = min(i0 + 1, 13);
}

__device__ inline float bilin_tap(const float* f, int y0, int y1, float ty,
                                  int x0, int x1, float tx) {
    float a = f[y0 * 14 + x0], b = f[y0 * 14 + x1];
    float c = f[y1 * 14 + x0], d = f[y1 * 14 + x1];
    return (1.f - ty) * ((1.f - tx) * a + tx * b) + ty * ((1.f - tx) * c + tx * d);
}

// ---------------------------------------------------------------- K0: align
__global__ __launch_bounds__(128) void align_kernel(const int* __restrict__ prev_b,
                                                    const int* __restrict__ first_b,
                                                    int* __restrict__ fb_al) {
    int b = blockIdx.x;
    int tid = threadIdx.x;
    __shared__ int dist[N_];
    __shared__ int bestIdx;
    if (tid < N_) {
        int s = 0;
        for (int j = 0; j < N_; ++j) {
            int src = (j - tid) % N_;
            if (src < 0) src += N_;
            int dy = prev_b[(b * N_ + j) * 2] - first_b[(b * N_ + src) * 2];
            int dx = prev_b[(b * N_ + j) * 2 + 1] - first_b[(b * N_ + src) * 2 + 1];
            s += abs(dy) + abs(dx);
        }
        dist[tid] = s;
    }
    __syncthreads();
    if (tid == 0) {
        int best = 0, bd = dist[0];
        for (int i = 1; i < N_; ++i)
            if (dist[i] < bd) { bd = dist[i]; best = i; }
        bestIdx = best;
    }
    __syncthreads();
    if (tid < N_) {
        int src = (tid - bestIdx) % N_;
        if (src < 0) src += N_;
        fb_al[(b * N_ + tid) * 2]     = first_b[(b * N_ + src) * 2];
        fb_al[(b * N_ + tid) * 2 + 1] = first_b[(b * N_ + src) * 2 + 1];
    }
}

// -------------------------------------------------- K1: pre_q/first_q gather
__global__ __launch_bounds__(256) void gather_init_kernel(
        const float* __restrict__ pre_f, const float* __restrict__ first_f,
        const int* __restrict__ prev_b, const int* __restrict__ fb_al,
        float* __restrict__ pre_q, float* __restrict__ first_q,
        float* __restrict__ curr) {
    int m = blockIdx.x;
    int b = m / N_;
    int tid = threadIdx.x;
    int py = prev_b[m * 2], px = prev_b[m * 2 + 1];
    int fy = fb_al[m * 2], fx = fb_al[m * 2 + 1];
    int py0, py1, px0, px1, fy0, fy1, fx0, fx1;
    float pty, ptx, fty, ftx;
    bilin_setup(py, py0, py1, pty);
    bilin_setup(px, px0, px1, ptx);
    bilin_setup(fy, fy0, fy1, fty);
    bilin_setup(fx, fx0, fx1, ftx);
    for (int c = tid; c < C_; c += 256) {
        const float* fp = pre_f + (size_t)(b * C_ + c) * 196;
        const float* ff = first_f + (size_t)(b * C_ + c) * 196;
        pre_q[(size_t)m * C_ + c]   = bilin_tap(fp, py0, py1, pty, px0, px1, ptx);
        first_q[(size_t)m * C_ + c] = bilin_tap(ff, fy0, fy1, fty, fx0, fx1, ftx);
    }
    if (tid < 2) curr[m * 2 + tid] = (float)prev_b[m * 2 + tid];
}

// -------------------------------------------------- K2: tokens = LN(cat)+pe
__global__ __launch_bounds__(256) void tokens_kernel(
        const float* __restrict__ curr_f, const float* __restrict__ pre_q,
        const float* __restrict__ first_q, const float* __restrict__ curr,
        const float* __restrict__ ln_g, const float* __restrict__ ln_b,
        float* __restrict__ tokens, short* __restrict__ tokens_bf) {
    int m = blockIdx.x;
    int b = m / N_;
    int n = m % N_;
    int tid = threadIdx.x;
    __shared__ float bf[C_];
    __shared__ float red[10];

    float cy = curr[m * 2], cx = curr[m * 2 + 1];
    int iy = (int)cy, ix = (int)cx;
    int y0, y1, x0, x1;
    float ty, tx;
    bilin_setup(iy, y0, y1, ty);
    bilin_setup(ix, x0, x1, tx);
    for (int c = tid; c < C_; c += 256) {
        const float* f = curr_f + (size_t)(b * C_ + c) * 196;
        bf[c] = bilin_tap(f, y0, y1, ty, x0, x1, tx);
    }
    __syncthreads();

    float s = 0.f, s2 = 0.f;
    for (int d = tid; d < D_; d += 256) {
        float v;
        if (d < C_)            v = pre_q[(size_t)m * C_ + d];
        else if (d < 2 * C_)   v = bf[d - C_];
        else if (d == 2 * C_)  v = cy;
        else if (d == 2*C_+1)  v = cx;
        else                   v = first_q[(size_t)m * C_ + (d - 2 * C_ - 2)];
        s += v; s2 += v * v;
    }
    block_reduce_2(s, s2, red);
    float mean = s / (float)D_;
    float var = s2 / (float)D_ - mean * mean;
    float inv = rsqrtf(var + EPS_);

    const float negLogDivD = -logf(10000.0f) / (float)D_;
    for (int d = tid; d < KPD_; d += 256) {
        if (d < D_) {
            float v;
            if (d < C_)            v = pre_q[(size_t)m * C_ + d];
            else if (d < 2 * C_)   v = bf[d - C_];
            else if (d == 2 * C_)  v = cy;
            else if (d == 2*C_+1)  v = cx;
            else                   v = first_q[(size_t)m * C_ + (d - 2 * C_ - 2)];
            float ln = ln_g[d] * (v - mean) * inv + ln_b[d];
            int kk = d >> 1;
            float ang = (float)n * expf((float)(2 * kk) * negLogDivD);
            float pe = (d & 1) ? cosf(ang) : sinf(ang);
            float val = ln + pe;
            tokens[(size_t)m * D_ + d] = val;
            tokens_bf[(size_t)m * KPD_ + d] = f2bf(val);
        } else {
            tokens_bf[(size_t)m * KPD_ + d] = 0;
        }
    }
}

// ---------------------------------- weight fp32 -> MFMA-fragment-packed bf16
// Wp[((strip*nch + chunk)*64 + lane)*8 + j] = W[strip*16 + (lane&15)]
//                                              [chunk*32 + (lane>>4)*8 + j]
// y-split 4-way for occupancy.
__global__ __launch_bounds__(256) void wpack_kernel(const float* __restrict__ w,
                                                    short* __restrict__ o,
                                                    int K, int O, int nch) {
    int s = blockIdx.x;
    int items = nch * 64;
    int qlen = (items + 3) >> 2;
    int beg = blockIdx.y * qlen;
    int end = min(items, beg + qlen);
    for (int idx = beg + threadIdx.x; idx < end; idx += 256) {
        int c = idx >> 6, l = idx & 63;
        int col = l & 15, quad = l >> 4;
        int orow = s * 16 + col;
        int k0 = c * 32 + quad * 8;
        bf16x8 v;
        if (orow < O && k0 + 8 <= K) {
            const float* src = w + (size_t)orow * K + k0;
            float2 a = *(const float2*)(src);
            float2 b = *(const float2*)(src + 2);
            float2 cc = *(const float2*)(src + 4);
            float2 d = *(const float2*)(src + 6);
            v[0] = f2bf(a.x);  v[1] = f2bf(a.y);
            v[2] = f2bf(b.x);  v[3] = f2bf(b.y);
            v[4] = f2bf(cc.x); v[5] = f2bf(cc.y);
            v[6] = f2bf(d.x);  v[7] = f2bf(d.y);
        } else {
#pragma unroll
            for (int j = 0; j < 8; ++j) {
                int k = k0 + j;
                v[j] = (orow < O && k < K) ? f2bf(w[(size_t)orow * K + k]) : (short)0;
            }
        }
        *(bf16x8*)(o + ((size_t)s * nch + c) * 512 + l * 8) = v;
    }
}

// --------------------------- LDS-staged GEMM on packed weights, k-split
// Block: 4*SW o-strips, all 160 m-rows. Per chunk the 32-k A-slice (10KB)
// is staged once into double-buffered LDS (1 barrier/chunk) and shared by
// all 4 waves; each wave owns SW strips x 10 m-tiles. Partials go to
// part[blockIdx.y] via plain coalesced stores; consumers fold the S-sum.
template <int SW>
__global__ __launch_bounds__(256) void gemm_stage(
        const short* __restrict__ A, const short* __restrict__ Wp,
        const float* __restrict__ bias, float* __restrict__ part,
        int KpA, int nch, int O, int per) {
    int cs = blockIdx.y * per;
    int ce = min(nch, cs + per);
    if (cs >= ce) return;
    int tid = threadIdx.x;
    int lane = tid & 63, wave = tid >> 6;
    int col = lane & 15, quad = lane >> 4;
    int s0 = (blockIdx.x * 4 + wave) * SW;

    __shared__ short lbuf[2][160 * 32];          // 20 KB, double-buffered

    // staging map: segment = m*4+part (16B each); 640 segs, 256 threads
    int m0 = tid >> 2, p8 = (tid & 3) * 8;
    int m1 = (tid + 256) >> 2;
    int m2 = (tid + 512) >> 2;
    const short* a0 = A + (size_t)m0 * KpA + p8;
    const short* a1 = A + (size_t)m1 * KpA + p8;
    const short* a2 = A + (size_t)m2 * KpA + p8;
    bf16x8 sr0, sr1, sr2;

    f32x4 acc[SW][10];
#pragma unroll
    for (int j = 0; j < SW; ++j)
#pragma unroll
        for (int t = 0; t < 10; ++t)
#pragma unroll
            for (int r = 0; r < 4; ++r) acc[j][t][r] = 0.f;

    const short* wbase[SW];
#pragma unroll
    for (int j = 0; j < SW; ++j)
        wbase[j] = Wp + (size_t)(s0 + j) * nch * 512 + lane * 8;
    bf16x8 wc[SW], wn[SW];

    // prologue: stage chunk cs, preload W(cs)
    sr0 = *(const bf16x8*)(a0 + cs * 32);
    sr1 = *(const bf16x8*)(a1 + cs * 32);
    if (tid < 128) sr2 = *(const bf16x8*)(a2 + cs * 32);
#pragma unroll
    for (int j = 0; j < SW; ++j)
        wc[j] = *(const bf16x8*)(wbase[j] + (size_t)cs * 512);
    *(bf16x8*)(&lbuf[0][m0 * 32 + p8]) = sr0;
    *(bf16x8*)(&lbuf[0][m1 * 32 + p8]) = sr1;
    if (tid < 128) *(bf16x8*)(&lbuf[0][m2 * 32 + p8]) = sr2;
    __syncthreads();

    int cur = 0;
    for (int c = cs; c < ce; ++c) {
        bool more = (c + 1) < ce;
        if (more) {                       // issue next-chunk loads early
            sr0 = *(const bf16x8*)(a0 + (c + 1) * 32);
            sr1 = *(const bf16x8*)(a1 + (c + 1) * 32);
            if (tid < 128) sr2 = *(const bf16x8*)(a2 + (c + 1) * 32);
#pragma unroll
            for (int j = 0; j < SW; ++j)
                wn[j] = *(const bf16x8*)(wbase[j] + (size_t)(c + 1) * 512);
        }
#pragma unroll
        for (int t = 0; t < 10; ++t) {
            bf16x8 af = *(const bf16x8*)(&lbuf[cur][t * 512 + col * 32 + quad * 8]);
#pragma unroll
            for (int j = 0; j < SW; ++j)
                acc[j][t] = __builtin_amdgcn_mfma_f32_16x16x32_bf16(af, wc[j], acc[j][t], 0, 0, 0);
        }
        if (more) {                       // write other buffer (its readers
            *(bf16x8*)(&lbuf[cur ^ 1][m0 * 32 + p8]) = sr0;   // passed last barrier)
            *(bf16x8*)(&lbuf[cur ^ 1][m1 * 32 + p8]) = sr1;
            if (tid < 128) *(bf16x8*)(&lbuf[cur ^ 1][m2 * 32 + p8]) = sr2;
        }
        __syncthreads();
#pragma unroll
        for (int j = 0; j < SW; ++j) wc[j] = wn[j];
        cur ^= 1;
    }

    float* pout = part + (size_t)blockIdx.y * M_ * O;
#pragma unroll
    for (int j = 0; j < SW; ++j) {
        int oc = (s0 + j) * 16 + col;
        if (oc < O) {
            float bv = (blockIdx.y == 0) ? bias[oc] : 0.f;
#pragma unroll
            for (int t = 0; t < 10; ++t)
#pragma unroll
                for (int r = 0; r < 4; ++r)
                    pout[(size_t)(t * 16 + quad * 4 + r) * O + oc] = acc[j][t][r] + bv;
        }
    }
}

// ------------------------------------------------ MFMA GEMM tier-1 (round-2)
__global__ __launch_bounds__(256) void gemm_pk(
        const short* __restrict__ A, const short* __restrict__ Wp,
        const float* __restrict__ bias, float* __restrict__ Cout,
        int KpA, int nch, int O) {
    int strip = blockIdx.x;
    int nsk = gridDim.y;
    int mg = blockIdx.z;
    int lane = threadIdx.x & 63, wave = threadIdx.x >> 6;
    int col = lane & 15, quad = lane >> 4;

    int per = (nch + nsk - 1) / nsk;
    int cs = blockIdx.y * per;
    int ce = min(nch, cs + per);
    if (cs >= ce) return;
    int tot = ce - cs;
    int qn = tot >> 2, rmd = tot & 3;
    int c0 = cs + wave * qn + min(wave, rmd);
    int c1 = c0 + qn + (wave < rmd ? 1 : 0);

    const short* wp = Wp + (size_t)strip * nch * 512 + lane * 8;
    const short* ap = A + (size_t)(mg * 80 + col) * KpA + quad * 8;

    f32x4 acc[5];
#pragma unroll
    for (int t = 0; t < 5; ++t)
#pragma unroll
        for (int r = 0; r < 4; ++r) acc[t][r] = 0.f;

    if (c0 < c1) {
        bf16x8 wcur = *(const bf16x8*)(wp + (size_t)c0 * 512);
        for (int c = c0; c < c1; ++c) {
            bf16x8 wnxt = wcur;
            if (c + 1 < c1) wnxt = *(const bf16x8*)(wp + (size_t)(c + 1) * 512);
#pragma unroll
            for (int t = 0; t < 5; ++t) {
                bf16x8 af = *(const bf16x8*)(ap + (size_t)t * 16 * KpA + c * 32);
                acc[t] = __builtin_amdgcn_mfma_f32_16x16x32_bf16(af, wcur, acc[t], 0, 0, 0);
            }
            wcur = wnxt;
        }
    }

    __shared__ f32x4 red[4][5][64];       // 20 KB
#pragma unroll
    for (int t = 0; t < 5; ++t) red[wave][t][lane] = acc[t];
    __syncthreads();
    for (int item = threadIdx.x; item < 320; item += 256) {
        int t = item >> 6, l2 = item & 63;
        f32x4 v = red[0][t][l2];
#pragma unroll
        for (int w = 1; w < 4; ++w)
#pragma unroll
            for (int r = 0; r < 4; ++r) v[r] += red[w][t][l2][r];
        int oc = strip * 16 + (l2 & 15);
        if (oc < O) {
            float bv = (blockIdx.y == 0) ? bias[oc] : 0.f;
            int rbase = mg * 80 + t * 16 + (l2 >> 4) * 4;
#pragma unroll
            for (int r = 0; r < 4; ++r) {
                float val = v[r] + bv;
                if (nsk == 1) Cout[(size_t)(rbase + r) * O + oc] = val;
                else atomicAdd(&Cout[(size_t)(rbase + r) * O + oc], val);
            }
        }
    }
}

// ------------------------------------------------ MFMA GEMM, fp32 W (tier-0)
__global__ __launch_bounds__(256) void gemm_mfma_sk(
        const short* __restrict__ A, const float* __restrict__ Wf,
        const float* __restrict__ bias, float* __restrict__ Cout,
        int K, int KpA, int O, int KC) {
    int kc0 = blockIdx.y * KC;
    if (kc0 >= K) return;
    int kend = min(K, kc0 + KC);

    int lane = threadIdx.x & 63;
    int wave = threadIdx.x >> 6;
    int col  = lane & 15;
    int quad = lane >> 4;
    int o0 = blockIdx.x * 128 + wave * 32 + col;
    int o1 = o0 + 16;
    int oc0 = min(o0, O - 1), oc1 = min(o1, O - 1);

    const float* wrow0 = Wf + (size_t)oc0 * K + quad * 8;
    const float* wrow1 = Wf + (size_t)oc1 * K + quad * 8;
    const short* abase = A + (size_t)col * KpA + quad * 8;

    f32x4 acc0[10], acc1[10];
#pragma unroll
    for (int t = 0; t < 10; ++t)
#pragma unroll
        for (int r = 0; r < 4; ++r) { acc0[t][r] = 0.f; acc1[t][r] = 0.f; }

    int nfull = (kend - kc0) >> 5;
    bf16x8 aCur[10];
    float2 wCur[8];
    if (nfull > 0) {
#pragma unroll
        for (int t = 0; t < 10; ++t)
            aCur[t] = *(const bf16x8*)(abase + (size_t)t * 16 * KpA + kc0);
#pragma unroll
        for (int j = 0; j < 4; ++j) {
            wCur[j]     = *(const float2*)(wrow0 + kc0 + 2 * j);
            wCur[4 + j] = *(const float2*)(wrow1 + kc0 + 2 * j);
        }
    }
    for (int i = 0; i < nfull; ++i) {
        bf16x8 aNxt[10];
        float2 wNxt[8];
        if (i + 1 < nfull) {
            int kn = kc0 + (i + 1) * 32;
#pragma unroll
            for (int t = 0; t < 10; ++t)
                aNxt[t] = *(const bf16x8*)(abase + (size_t)t * 16 * KpA + kn);
#pragma unroll
            for (int j = 0; j < 4; ++j) {
                wNxt[j]     = *(const float2*)(wrow0 + kn + 2 * j);
                wNxt[4 + j] = *(const float2*)(wrow1 + kn + 2 * j);
            }
        }
        bf16x8 b0, b1;
#pragma unroll
        for (int j = 0; j < 4; ++j) {
            b0[2*j] = f2bf(wCur[j].x);     b0[2*j+1] = f2bf(wCur[j].y);
            b1[2*j] = f2bf(wCur[4+j].x);   b1[2*j+1] = f2bf(wCur[4+j].y);
        }
#pragma unroll
        for (int t = 0; t < 10; ++t) {
            acc0[t] = __builtin_amdgcn_mfma_f32_16x16x32_bf16(aCur[t], b0, acc0[t], 0, 0, 0);
            acc1[t] = __builtin_amdgcn_mfma_f32_16x16x32_bf16(aCur[t], b1, acc1[t], 0, 0, 0);
        }
#pragma unroll
        for (int t = 0; t < 10; ++t) aCur[t] = aNxt[t];
#pragma unroll
        for (int j = 0; j < 8; ++j) wCur[j] = wNxt[j];
    }
    int kmain = kc0 + nfull * 32;
    if (kmain < kend) {
        bf16x8 b0, b1;
#pragma unroll
        for (int j = 0; j < 8; ++j) {
            int k = kmain + quad * 8 + j;
            b0[j] = (k < kend) ? f2bf(Wf[(size_t)oc0 * K + k]) : (short)0;
            b1[j] = (k < kend) ? f2bf(Wf[(size_t)oc1 * K + k]) : (short)0;
        }
#pragma unroll
        for (int t = 0; t < 10; ++t) {
            bf16x8 af = *(const bf16x8*)(abase + (size_t)t * 16 * KpA + kmain);
            acc0[t] = __builtin_amdgcn_mfma_f32_16x16x32_bf16(af, b0, acc0[t], 0, 0, 0);
            acc1[t] = __builtin_amdgcn_mfma_f32_16x16x32_bf16(af, b1, acc1[t], 0, 0, 0);
        }
    }
    if (o0 < O) {
        float bv = (blockIdx.y == 0) ? bias[o0] : 0.f;
#pragma unroll
        for (int t = 0; t < 10; ++t)
#pragma unroll
            for (int r = 0; r < 4; ++r)
                atomicAdd(&Cout[(size_t)(t * 16 + quad * 4 + r) * O + o0], acc0[t][r] + bv);
    }
    if (o1 < O) {
        float bv = (blockIdx.y == 0) ? bias[o1] : 0.f;
#pragma unroll
        for (int t = 0; t < 10; ++t)
#pragma unroll
            for (int r = 0; r < 4; ++r)
                atomicAdd(&Cout[(size_t)(t * 16 + quad * 4 + r) * O + o1], acc1[t][r] + bv);
    }
}

// ------------------------------------ relu + bf16 convert (ff1), S-way fold
__global__ __launch_bounds__(256) void relu_cvt_kernel(const float* __restrict__ in,
                                                       int S, size_t sstr,
                                                       short* __restrict__ out,
                                                       int n) {
    int i = blockIdx.x * 256 + threadIdx.x;
    if (i < n) {
        float v = 0.f;
        for (int s = 0; s < S; ++s) v += in[(size_t)s * sstr + i];
        out[i] = f2bf(fmaxf(v, 0.f));
    }
}

// ------------------------------- qkv partials -> padded bf16 q/k/v, S-fold
__global__ __launch_bounds__(256) void qkv_cvt_kernel(const float* __restrict__ part,
                                                      int S,
                                                      short* __restrict__ q_bf,
                                                      short* __restrict__ k_bf,
                                                      short* __restrict__ v_bf) {
    int m = blockIdx.x;
    int b = m / N_, q = m % N_;
    for (int d = threadIdx.x; d < KPD_; d += 256) {
        short qv = 0, kv = 0, vv = 0;
        if (d < D_) {
            float qf = 0.f, kf = 0.f, vf = 0.f;
            for (int s = 0; s < S; ++s) {
                const float* p = part + (size_t)s * M_ * QKV_ + (size_t)m * QKV_;
                qf += p[d]; kf += p[D_ + d]; vf += p[2 * D_ + d];
            }
            qv = f2bf(qf); kv = f2bf(kf); vv = f2bf(vf);
        }
        q_bf[(size_t)m * KPD_ + d] = qv;
        k_bf[(size_t)m * KPD_ + d] = kv;
        v_bf[((size_t)b * 96 + q) * KPD_ + d] = vv;
    }
}

// ------------------------------------------------ scores = Q·K^T via MFMA
__global__ __launch_bounds__(256) void scores_mfma(const short* __restrict__ q_bf,
                                                   const short* __restrict__ k_bf,
                                                   float* __restrict__ sc) {
    int bi = blockIdx.x;
    int b = bi / 25, qt = (bi % 25) / 5, kt = bi % 5;
    int lane = threadIdx.x & 63, wave = threadIdx.x >> 6;
    int col = lane & 15, quad = lane >> 4;
    const short* qbase = q_bf + (size_t)(b * N_ + qt * 16 + col) * KPD_ + quad * 8;
    const short* kbase = k_bf + (size_t)(b * N_ + kt * 16 + col) * KPD_ + quad * 8;
    f32x4 acc;
#pragma unroll
    for (int r = 0; r < 4; ++r) acc[r] = 0.f;
    int c0 = wave * 25, c1 = min(97, c0 + 25);
    for (int c = c0; c < c1; ++c) {
        bf16x8 af = *(const bf16x8*)(qbase + c * 32);
        bf16x8 bf8 = *(const bf16x8*)(kbase + c * 32);
        acc = __builtin_amdgcn_mfma_f32_16x16x32_bf16(af, bf8, acc, 0, 0, 0);
    }
    __shared__ f32x4 red[4][64];
    red[wave][lane] = acc;
    __syncthreads();
    if (threadIdx.x < 64) {
        f32x4 t = red[0][lane];
#pragma unroll
        for (int w = 1; w < 4; ++w)
#pragma unroll
            for (int r = 0; r < 4; ++r) t[r] += red[w][lane][r];
        float scale = rsqrtf((float)D_);
#pragma unroll
        for (int r = 0; r < 4; ++r)
            sc[(size_t)(b * N_ + qt * 16 + quad * 4 + r) * N_ + kt * 16 + col] = t[r] * scale;
    }
}

// ------------------------------------------------ softmax -> p_bf [M_][96]
__global__ __launch_bounds__(256) void softmax_kernel(const float* __restrict__ sc,
                                                      short* __restrict__ p_bf) {
    int m = blockIdx.x * 4 + (threadIdx.x >> 6);
    int lane = threadIdx.x & 63;
    const float* row = sc + (size_t)m * N_;
    float a = row[lane];
    float bv = (lane < 16) ? row[64 + lane] : -1e30f;
    float mx = wave_max(fmaxf(a, bv));
    mx = __shfl(mx, 0, 64);
    float e0 = expf(a - mx);
    float e1 = (lane < 16) ? expf(bv - mx) : 0.f;
    float sum = wave_sum(e0 + e1);
    sum = __shfl(sum, 0, 64);
    float rs = 1.0f / sum;
    p_bf[(size_t)m * 96 + lane] = f2bf(e0 * rs);
    if (lane < 32)
        p_bf[(size_t)m * 96 + 64 + lane] = (lane < 16) ? f2bf(e1 * rs) : (short)0;
}

// ------------------------------------------------ av = P·V via MFMA
__global__ __launch_bounds__(256) void av_mfma(const short* __restrict__ p_bf,
                                               const short* __restrict__ v_bf,
                                               short* __restrict__ av_bf) {
    int bi = blockIdx.x;
    int b = bi / 49, g = bi % 49;
    int lane = threadIdx.x & 63, wave = threadIdx.x >> 6;
    int dtile = g * 4 + wave;
    if (dtile >= 194) return;
    int d0 = dtile * 16;
    int col = lane & 15, quad = lane >> 4;
    const short* pbase = p_bf + (size_t)b * N_ * 96 + quad * 8;
    const short* vb = v_bf + (size_t)b * 96 * KPD_ + d0 + col;
    f32x4 acc[5];
#pragma unroll
    for (int t = 0; t < 5; ++t)
#pragma unroll
        for (int r = 0; r < 4; ++r) acc[t][r] = 0.f;
#pragma unroll
    for (int c = 0; c < 3; ++c) {
        bf16x8 bf8;
#pragma unroll
        for (int j = 0; j < 8; ++j)
            bf8[j] = vb[(size_t)(c * 32 + quad * 8 + j) * KPD_];
#pragma unroll
        for (int t = 0; t < 5; ++t) {
            bf16x8 af = *(const bf16x8*)(pbase + (size_t)(t * 16 + col) * 96 + c * 32);
            acc[t] = __builtin_amdgcn_mfma_f32_16x16x32_bf16(af, bf8, acc[t], 0, 0, 0);
        }
    }
#pragma unroll
    for (int t = 0; t < 5; ++t)
#pragma unroll
        for (int r = 0; r < 4; ++r)
            av_bf[(size_t)(b * N_ + t * 16 + quad * 4 + r) * KPD_ + d0 + col] = f2bf(acc[t][r]);
}

// ------------------------------------------- layernorm, S-way partial fold
template <bool WF32>
__global__ __launch_bounds__(256) void ln_kernel(const float* __restrict__ xin,
                                                 int S, size_t sstr,
                                                 const float* __restrict__ res,
                                                 const float* __restrict__ g,
                                                 const float* __restrict__ bta,
                                                 float* __restrict__ outf,
                                                 short* __restrict__ outb) {
    int m = blockIdx.x;
    int tid = threadIdx.x;
    __shared__ float red[10];
    const float* xr = xin + (size_t)m * D_;
    const float* rr = res + (size_t)m * D_;
    float vv[13];
    float s = 0.f, s2 = 0.f;
#pragma unroll
    for (int i = 0; i < 13; ++i) {
        int d = tid + i * 256;
        float v = 0.f;
        if (d < D_) {
            v = rr[d];
            for (int sp = 0; sp < S; ++sp) v += xr[(size_t)sp * sstr + d];
            s += v; s2 += v * v;
        }
        vv[i] = v;
    }
    block_reduce_2(s, s2, red);
    float mean = s / (float)D_;
    float var = s2 / (float)D_ - mean * mean;
    float inv = rsqrtf(var + EPS_);
#pragma unroll
    for (int i = 0; i < 13; ++i) {
        int d = tid + i * 256;
        if (d < D_) {
            float y = g[d] * (vv[i] - mean) * inv + bta[d];
            if (WF32) outf[(size_t)m * D_ + d] = y;
            outb[(size_t)m * KPD_ + d] = f2bf(y);
        } else if (d < KPD_) {
            outb[(size_t)m * KPD_ + d] = 0;
        }
    }
}

// ---------------------------------------------------------------- update
__global__ __launch_bounds__(256) void update_kernel(const float* __restrict__ part,
                                                     int S, size_t sstr,
                                                     float* __restrict__ curr,
                                                     float* __restrict__ pre_q,
                                                     float* __restrict__ results) {
    int m = blockIdx.x;
    int tid = threadIdx.x;
    const float* pr = part + (size_t)m * OD_;
    for (int c = tid; c < C_; c += 256) {
        float v = 0.f;
        for (int s = 0; s < S; ++s) v += pr[(size_t)s * sstr + c];
        pre_q[(size_t)m * C_ + c] += v;
    }
    if (tid < 2) {
        float v = 0.f;
        for (int s = 0; s < S; ++s) v += pr[(size_t)s * sstr + C_ + tid];
        float nc = curr[m * 2 + tid] + v;
        nc = fminf(fmaxf(nc, 0.f), 223.f);
        curr[m * 2 + tid] = nc;
        results[m * 2 + tid] = nc;
    }
}

// ---------------------------------------------------------------- launch
extern "C" void kernel_launch(void* const* d_in, const int* in_sizes, int n_in,
                              void* d_out, int out_size, void* d_ws, size_t ws_size,
                              hipStream_t stream) {
    const float* pre_f   = (const float*)d_in[0];
    const float* curr_f  = (const float*)d_in[1];
    const float* first_f = (const float*)d_in[2];
    const int*   prev_b  = (const int*)d_in[3];
    const int*   first_b = (const int*)d_in[4];
    const float* ln_g    = (const float*)d_in[5];
    const float* ln_b    = (const float*)d_in[6];
    const float* ipw     = (const float*)d_in[7];
    const float* ipb     = (const float*)d_in[8];
    const float* opw     = (const float*)d_in[9];
    const float* opb     = (const float*)d_in[10];
    const float* n1g     = (const float*)d_in[11];
    const float* n1b     = (const float*)d_in[12];
    const float* l1w     = (const float*)d_in[13];
    const float* l1b     = (const float*)d_in[14];
    const float* l2w     = (const float*)d_in[15];
    const float* l2b     = (const float*)d_in[16];
    const float* n2g     = (const float*)d_in[17];
    const float* n2b     = (const float*)d_in[18];
    const float* ow      = (const float*)d_in[19];
    const float* ob      = (const float*)d_in[20];
    float* outp = (float*)d_out;

    float* wf = (float*)d_ws;
    size_t off = 0;
    // ---- common buffers
    int*   fb_al   = (int*)(wf + off); off += 320;
    float* curr    = wf + off;         off += 320;
    float* pre_q   = wf + off;         off += (size_t)M_ * C_;
    float* first_q = wf + off;         off += (size_t)M_ * C_;
    float* tokens  = wf + off;         off += (size_t)M_ * D_;
    float* xbuf    = wf + off;         off += (size_t)M_ * D_;
    float* sc      = wf + off;         off += (size_t)M_ * N_;
    short* tokens_bf = (short*)(wf + off); off += (size_t)M_ * KPD_ / 2;
    short* x_bf      = (short*)(wf + off); off += (size_t)M_ * KPD_ / 2;
    short* x2_bf     = (short*)(wf + off); off += (size_t)M_ * KPD_ / 2;
    short* av_bf     = (short*)(wf + off); off += (size_t)M_ * KPD_ / 2;
    short* ff1_bf    = (short*)(wf + off); off += (size_t)M_ * DFF_ / 2;
    short* q_bf      = (short*)(wf + off); off += (size_t)M_ * KPD_ / 2;
    short* k_bf      = (short*)(wf + off); off += (size_t)M_ * KPD_ / 2;
    short* v_bf      = (short*)(wf + off); off += (size_t)B_ * 96 * KPD_ / 2;
    short* p_bf      = (short*)(wf + off); off += (size_t)M_ * 96 / 2;
    size_t commonF = off;

    // ---- tier-2 layout: padded packed weights + partial scratch
    size_t o2 = commonF;
    short* ipw_p2 = (short*)(wf + o2); o2 += (size_t)584 * 97 * 256;
    short* opw_p2 = (short*)(wf + o2); o2 += (size_t)200 * 97 * 256;
    short* l1w_p2 = (short*)(wf + o2); o2 += (size_t)128 * 97 * 256;
    short* l2w_p2 = (short*)(wf + o2); o2 += (size_t)200 * 64 * 256;
    short* ow_p2  = (short*)(wf + o2); o2 += (size_t)68  * 97 * 256;
    float* gpart  = wf + o2;           o2 += (size_t)SQKV * M_ * QKV_;

    // ---- tier-1 layout: fp32 GEMM outs + exact packed weights (round-2)
    size_t o1 = commonF;
    float* qkv   = wf + o1; o1 += (size_t)M_ * QKV_;
    float* aout  = wf + o1; o1 += (size_t)M_ * D_;
    float* ff1f  = wf + o1; o1 += (size_t)M_ * DFF_;
    float* ffout = wf + o1; o1 += (size_t)M_ * D_;
    float* outb  = wf + o1; o1 += (size_t)M_ * OD_;
    size_t o0 = o1;                       // tier-0 ends here
    short* ipw_p1 = (short*)(wf + o1); o1 += (size_t)577 * 97 * 256;
    short* opw_p1 = (short*)(wf + o1); o1 += (size_t)193 * 97 * 256;
    short* l1w_p1 = (short*)(wf + o1); o1 += (size_t)128 * 97 * 256;
    short* l2w_p1 = (short*)(wf + o1); o1 += (size_t)193 * 64 * 256;
    short* ow_p1  = (short*)(wf + o1); o1 += (size_t)65  * 97 * 256;

    int tier = (ws_size >= o2 * sizeof(float)) ? 2
             : (ws_size >= o1 * sizeof(float)) ? 1
             : 0;
    (void)in_sizes; (void)n_in; (void)out_size; (void)o0;

    hipLaunchKernelGGL(align_kernel, dim3(B_), dim3(128), 0, stream,
                       prev_b, first_b, fb_al);
    hipLaunchKernelGGL(gather_init_kernel, dim3(M_), dim3(256), 0, stream,
                       pre_f, first_f, prev_b, fb_al, pre_q, first_q, curr);
    hipMemsetAsync(v_bf, 0, (size_t)B_ * 96 * KPD_ * 2, stream);

    if (tier == 2) {
        hipLaunchKernelGGL(wpack_kernel, dim3(584, 4), dim3(256), 0, stream, ipw, ipw_p2, D_, QKV_, 97);
        hipLaunchKernelGGL(wpack_kernel, dim3(200, 4), dim3(256), 0, stream, opw, opw_p2, D_, D_, 97);
        hipLaunchKernelGGL(wpack_kernel, dim3(128, 4), dim3(256), 0, stream, l1w, l1w_p2, D_, DFF_, 97);
        hipLaunchKernelGGL(wpack_kernel, dim3(200, 4), dim3(256), 0, stream, l2w, l2w_p2, DFF_, D_, 64);
        hipLaunchKernelGGL(wpack_kernel, dim3(68, 4),  dim3(256), 0, stream, ow, ow_p2, D_, OD_, 97);
    } else if (tier == 1) {
        hipLaunchKernelGGL(wpack_kernel, dim3(577, 4), dim3(256), 0, stream, ipw, ipw_p1, D_, QKV_, 97);
        hipLaunchKernelGGL(wpack_kernel, dim3(193, 4), dim3(256), 0, stream, opw, opw_p1, D_, D_, 97);
        hipLaunchKernelGGL(wpack_kernel, dim3(128, 4), dim3(256), 0, stream, l1w, l1w_p1, D_, DFF_, 97);
        hipLaunchKernelGGL(wpack_kernel, dim3(193, 4), dim3(256), 0, stream, l2w, l2w_p1, DFF_, D_, 64);
        hipLaunchKernelGGL(wpack_kernel, dim3(65, 4),  dim3(256), 0, stream, ow, ow_p1, D_, OD_, 97);
    }

    for (int it = 0; it < 3; ++it) {
        if (tier < 2) {
            if (tier == 0) hipMemsetAsync(qkv, 0, (size_t)M_ * QKV_ * 4, stream);
            hipMemsetAsync(aout,  0, (size_t)M_ * D_   * 4, stream);
            hipMemsetAsync(ff1f,  0, (size_t)M_ * DFF_ * 4, stream);
            hipMemsetAsync(ffout, 0, (size_t)M_ * D_   * 4, stream);
            hipMemsetAsync(outb,  0, (size_t)M_ * OD_  * 4, stream);
        }

        hipLaunchKernelGGL(tokens_kernel, dim3(M_), dim3(256), 0, stream,
                           curr_f, pre_q, first_q, curr, ln_g, ln_b, tokens, tokens_bf);
        // ---------------- qkv
        if (tier == 2)
            hipLaunchKernelGGL((gemm_stage<2>), dim3(73, SQKV), dim3(256), 0, stream,
                               tokens_bf, ipw_p2, ipb, gpart, KPD_, 97, QKV_, (97 + SQKV - 1) / SQKV);
        else if (tier == 1)
            hipLaunchKernelGGL(gemm_pk, dim3(577, 1, 2), dim3(256), 0, stream,
                               tokens_bf, ipw_p1, ipb, qkv, KPD_, 97, QKV_);
        else
            hipLaunchKernelGGL(gemm_mfma_sk, dim3(73, 6), dim3(256), 0, stream,
                               tokens_bf, ipw, ipb, qkv, D_, KPD_, QKV_, 544);
        hipLaunchKernelGGL(qkv_cvt_kernel, dim3(M_), dim3(256), 0, stream,
                           (tier == 2) ? gpart : qkv, (tier == 2) ? SQKV : 1,
                           q_bf, k_bf, v_bf);
        hipLaunchKernelGGL(scores_mfma, dim3(50), dim3(256), 0, stream,
                           q_bf, k_bf, sc);
        hipLaunchKernelGGL(softmax_kernel, dim3(40), dim3(256), 0, stream,
                           sc, p_bf);
        hipLaunchKernelGGL(av_mfma, dim3(98), dim3(256), 0, stream,
                           p_bf, v_bf, av_bf);
        // ---------------- out-proj
        if (tier == 2)
            hipLaunchKernelGGL((gemm_stage<2>), dim3(25, SOP), dim3(256), 0, stream,
                               av_bf, opw_p2, opb, gpart, KPD_, 97, D_, (97 + SOP - 1) / SOP);
        else if (tier == 1)
            hipLaunchKernelGGL(gemm_pk, dim3(193, 2, 2), dim3(256), 0, stream,
                               av_bf, opw_p1, opb, aout, KPD_, 97, D_);
        else
            hipLaunchKernelGGL(gemm_mfma_sk, dim3(25, 10), dim3(256), 0, stream,
                               av_bf, opw, opb, aout, D_, KPD_, D_, 320);
        hipLaunchKernelGGL((ln_kernel<true>), dim3(M_), dim3(256), 0, stream,
                           (tier == 2) ? gpart : aout, (tier == 2) ? SOP : 1, (size_t)M_ * D_,
                           tokens, n1g, n1b, xbuf, x_bf);
        // ---------------- ff1
        if (tier == 2)
            hipLaunchKernelGGL((gemm_stage<2>), dim3(16, SFF1), dim3(256), 0, stream,
                               x_bf, l1w_p2, l1b, gpart, KPD_, 97, DFF_, (97 + SFF1 - 1) / SFF1);
        else if (tier == 1)
            hipLaunchKernelGGL(gemm_pk, dim3(128, 2, 2), dim3(256), 0, stream,
                               x_bf, l1w_p1, l1b, ff1f, KPD_, 97, DFF_);
        else
            hipLaunchKernelGGL(gemm_mfma_sk, dim3(16, 17), dim3(256), 0, stream,
                               x_bf, l1w, l1b, ff1f, D_, KPD_, DFF_, 192);
        hipLaunchKernelGGL(relu_cvt_kernel, dim3((M_ * DFF_ + 255) / 256), dim3(256), 0, stream,
                           (tier == 2) ? gpart : ff1f, (tier == 2) ? SFF1 : 1, (size_t)M_ * DFF_,
                           ff1_bf, M_ * DFF_);
        // ---------------- ff2
        if (tier == 2)
            hipLaunchKernelGGL((gemm_stage<2>), dim3(25, SFF2), dim3(256), 0, stream,
                               ff1_bf, l2w_p2, l2b, gpart, DFF_, 64, D_, (64 + SFF2 - 1) / SFF2);
        else if (tier == 1)
            hipLaunchKernelGGL(gemm_pk, dim3(193, 2, 2), dim3(256), 0, stream,
                               ff1_bf, l2w_p1, l2b, ffout, DFF_, 64, D_);
        else
            hipLaunchKernelGGL(gemm_mfma_sk, dim3(25, 11), dim3(256), 0, stream,
                               ff1_bf, l2w, l2b, ffout, DFF_, DFF_, D_, 192);
        hipLaunchKernelGGL((ln_kernel<false>), dim3(M_), dim3(256), 0, stream,
                           (tier == 2) ? gpart : ffout, (tier == 2) ? SFF2 : 1, (size_t)M_ * D_,
                           xbuf, n2g, n2b, (float*)nullptr, x2_bf);
        // ---------------- head
        if (tier == 2)
            hipLaunchKernelGGL((gemm_stage<1>), dim3(17, SHD), dim3(256), 0, stream,
                               x2_bf, ow_p2, ob, gpart, KPD_, 97, OD_, (97 + SHD - 1) / SHD);
        else if (tier == 1)
            hipLaunchKernelGGL(gemm_pk, dim3(65, 4, 2), dim3(256), 0, stream,
                               x2_bf, ow_p1, ob, outb, KPD_, 97, OD_);
        else
            hipLaunchKernelGGL(gemm_mfma_sk, dim3(9, 13), dim3(256), 0, stream,
                               x2_bf, ow, ob, outb, D_, KPD_, OD_, 256);
        hipLaunchKernelGGL(update_kernel, dim3(M_), dim3(256), 0, stream,
                           (tier == 2) ? gpart : outb, (tier == 2) ? SHD : 1, (size_t)M_ * OD_,
                           curr, pre_q, outp + (size_t)it * M_ * 2);
    }
}

// Round 4
// 1089.971 us; speedup vs baseline: 1.0400x; 1.0400x over previous
//
#include <hip/hip_runtime.h>
#include <math.h>

#define B_    2
#define C_    1024
#define N_    80
#define D_    3074
#define DFF_  2048
#define OD_   1026      // C+2
#define QKV_  9222      // 3*D
#define M_    160       // B*N token rows
#define EPS_  1e-5f
#define KPD_  3104      // D_ rounded up to multiple of 32 (bf16 row stride)
#define SPL_  4         // split-K factor for all staged GEMMs

typedef __attribute__((ext_vector_type(8))) short bf16x8;   // 8 bf16 = 4 VGPRs
typedef __attribute__((ext_vector_type(4))) float f32x4;

// fp32 -> bf16 (round-to-nearest-even), bit pattern as short
__device__ inline short f2bf(float f) {
    unsigned u = __float_as_uint(f);
    u += 0x7fffu + ((u >> 16) & 1u);
    return (short)(u >> 16);
}

// ---------------------------------------------------------------- reductions
__device__ inline float wave_sum(float v) {
#pragma unroll
    for (int off = 32; off > 0; off >>= 1) v += __shfl_down(v, off, 64);
    return v;
}

__device__ inline float wave_max(float v) {
#pragma unroll
    for (int off = 32; off > 0; off >>= 1) v = fmaxf(v, __shfl_down(v, off, 64));
    return v;
}

__device__ inline void block_reduce_2(float& s, float& s2, float* red) {
    int tid = threadIdx.x;
    int lane = tid & 63, wid = tid >> 6;
    s = wave_sum(s);
    s2 = wave_sum(s2);
    if (lane == 0) { red[wid] = s; red[4 + wid] = s2; }
    __syncthreads();
    if (tid == 0) {
        red[8] = red[0] + red[1] + red[2] + red[3];
        red[9] = red[4] + red[5] + red[6] + red[7];
    }
    __syncthreads();
    s = red[8]; s2 = red[9];
}

// ---------------------------------------------------------------- bilinear
__device__ inline void bilin_setup(int p, int& i0, int& i1, float& t) {
    float s = (p + 0.5f) * 0.0625f - 0.5f;
    s = fminf(fmaxf(s, 0.0f), 13.0f);
    i0 = (int)s;
    t = s - (float)i0;
    i1 = min(i0 + 1, 13);
}

__device__ inline float bilin_tap(const float* f, int y0, int y1, float ty,
                                  int x0, int x1, float tx) {
    float a = f[y0 * 14 + x0], b = f[y0 * 14 + x1];
    float c = f[y1 * 14 + x0], d = f[y1 * 14 + x1];
    return (1.f - ty) * ((1.f - tx) * a + tx * b) + ty * ((1.f - tx) * c + tx * d);
}

// ---------------------------------------------------------------- K0: align
__global__ __launch_bounds__(128) void align_kernel(const int* __restrict__ prev_b,
                                                    const int* __restrict__ first_b,
                                                    int* __restrict__ fb_al) {
    int b = blockIdx.x;
    int tid = threadIdx.x;
    __shared__ int dist[N_];
    __shared__ int bestIdx;
    if (tid < N_) {
        int s = 0;
        for (int j = 0; j < N_; ++j) {
            int src = (j - tid) % N_;
            if (src < 0) src += N_;
            int dy = prev_b[(b * N_ + j) * 2] - first_b[(b * N_ + src) * 2];
            int dx = prev_b[(b * N_ + j) * 2 + 1] - first_b[(b * N_ + src) * 2 + 1];
            s += abs(dy) + abs(dx);
        }
        dist[tid] = s;
    }
    __syncthreads();
    if (tid == 0) {
        int best = 0, bd = dist[0];
        for (int i = 1; i < N_; ++i)
            if (dist[i] < bd) { bd = dist[i]; best = i; }
        bestIdx = best;
    }
    __syncthreads();
    if (tid < N_) {
        int src = (tid - bestIdx) % N_;
        if (src < 0) src += N_;
        fb_al[(b * N_ + tid) * 2]     = first_b[(b * N_ + src) * 2];
        fb_al[(b * N_ + tid) * 2 + 1] = first_b[(b * N_ + src) * 2 + 1];
    }
}

// -------------------------------------------------- K1: pre_q/first_q gather
__global__ __launch_bounds__(256) void gather_init_kernel(
        const float* __restrict__ pre_f, const float* __restrict__ first_f,
        const int* __restrict__ prev_b, const int* __restrict__ fb_al,
        float* __restrict__ pre_q, float* __restrict__ first_q,
        float* __restrict__ curr) {
    int m = blockIdx.x;
    int b = m / N_;
    int tid = threadIdx.x;
    int py = prev_b[m * 2], px = prev_b[m * 2 + 1];
    int fy = fb_al[m * 2], fx = fb_al[m * 2 + 1];
    int py0, py1, px0, px1, fy0, fy1, fx0, fx1;
    float pty, ptx, fty, ftx;
    bilin_setup(py, py0, py1, pty);
    bilin_setup(px, px0, px1, ptx);
    bilin_setup(fy, fy0, fy1, fty);
    bilin_setup(fx, fx0, fx1, ftx);
    for (int c = tid; c < C_; c += 256) {
        const float* fp = pre_f + (size_t)(b * C_ + c) * 196;
        const float* ff = first_f + (size_t)(b * C_ + c) * 196;
        pre_q[(size_t)m * C_ + c]   = bilin_tap(fp, py0, py1, pty, px0, px1, ptx);
        first_q[(size_t)m * C_ + c] = bilin_tap(ff, fy0, fy1, fty, fx0, fx1, ftx);
    }
    if (tid < 2) curr[m * 2 + tid] = (float)prev_b[m * 2 + tid];
}

// ----------------------------------------------- positional-encoding table
__global__ __launch_bounds__(256) void pe_kernel(float* __restrict__ pe) {
    int n = blockIdx.x;
    const float negLogDivD = -logf(10000.0f) / (float)D_;
    for (int d = threadIdx.x; d < D_; d += 256) {
        int kk = d >> 1;
        float ang = (float)n * expf((float)(2 * kk) * negLogDivD);
        pe[(size_t)n * D_ + d] = (d & 1) ? cosf(ang) : sinf(ang);
    }
}

// -------------------------------------------------- K2: tokens = LN(cat)+pe
__global__ __launch_bounds__(256) void tokens_kernel(
        const float* __restrict__ curr_f, const float* __restrict__ pre_q,
        const float* __restrict__ first_q, const float* __restrict__ curr,
        const float* __restrict__ ln_g, const float* __restrict__ ln_b,
        const float* __restrict__ pe_tab,
        float* __restrict__ tokens, short* __restrict__ tokens_bf) {
    int m = blockIdx.x;
    int b = m / N_;
    int n = m % N_;
    int tid = threadIdx.x;
    __shared__ float bf[C_];
    __shared__ float red[10];

    float cy = curr[m * 2], cx = curr[m * 2 + 1];
    int iy = (int)cy, ix = (int)cx;
    int y0, y1, x0, x1;
    float ty, tx;
    bilin_setup(iy, y0, y1, ty);
    bilin_setup(ix, x0, x1, tx);
    for (int c = tid; c < C_; c += 256) {
        const float* f = curr_f + (size_t)(b * C_ + c) * 196;
        bf[c] = bilin_tap(f, y0, y1, ty, x0, x1, tx);
    }
    __syncthreads();

    float s = 0.f, s2 = 0.f;
    for (int d = tid; d < D_; d += 256) {
        float v;
        if (d < C_)            v = pre_q[(size_t)m * C_ + d];
        else if (d < 2 * C_)   v = bf[d - C_];
        else if (d == 2 * C_)  v = cy;
        else if (d == 2*C_+1)  v = cx;
        else                   v = first_q[(size_t)m * C_ + (d - 2 * C_ - 2)];
        s += v; s2 += v * v;
    }
    block_reduce_2(s, s2, red);
    float mean = s / (float)D_;
    float var = s2 / (float)D_ - mean * mean;
    float inv = rsqrtf(var + EPS_);

    for (int d = tid; d < KPD_; d += 256) {
        if (d < D_) {
            float v;
            if (d < C_)            v = pre_q[(size_t)m * C_ + d];
            else if (d < 2 * C_)   v = bf[d - C_];
            else if (d == 2 * C_)  v = cy;
            else if (d == 2*C_+1)  v = cx;
            else                   v = first_q[(size_t)m * C_ + (d - 2 * C_ - 2)];
            float ln = ln_g[d] * (v - mean) * inv + ln_b[d];
            float val = ln + pe_tab[(size_t)n * D_ + d];
            tokens[(size_t)m * D_ + d] = val;
            tokens_bf[(size_t)m * KPD_ + d] = f2bf(val);
        } else {
            tokens_bf[(size_t)m * KPD_ + d] = 0;
        }
    }
}

// ---------------------------------- weight fp32 -> MFMA-fragment-packed bf16
// Wp[((strip*nch + chunk)*64 + lane)*8 + j] = W[strip*16 + (lane&15)]
//                                              [chunk*32 + (lane>>4)*8 + j]
// Coalesced row reads staged through LDS; packed writes contiguous.
#define WPK_CH 25
__global__ __launch_bounds__(256) void wpack_kernel(const float* __restrict__ w,
                                                    short* __restrict__ o,
                                                    int K, int O, int nch) {
    int s = blockIdx.x;
    int nq = (nch + 3) >> 2;
    int c0 = blockIdx.y * nq;
    int c1 = min(nch, c0 + nq);
    int ncq = c1 - c0;
    if (ncq <= 0) return;
    __shared__ short lds[16][WPK_CH * 32 + 8];   // 16 x 808 shorts = 25.9 KB

    int kbase = c0 * 32;
    int ktot = ncq * 32;                 // <= 800, even
    int npair = ktot >> 1;
    for (int idx = threadIdx.x; idx < 16 * npair; idx += 256) {
        int r = idx / npair;
        int kp = idx % npair;
        int orow = s * 16 + r;
        int k = kbase + kp * 2;
        float2 v = make_float2(0.f, 0.f);
        if (orow < O && k + 1 < K)
            v = *(const float2*)(w + (size_t)orow * K + k);
        lds[r][kp * 2]     = f2bf(v.x);
        lds[r][kp * 2 + 1] = f2bf(v.y);
    }
    __syncthreads();
    for (int idx = threadIdx.x; idx < ncq * 64; idx += 256) {
        int ci = idx >> 6, l = idx & 63;
        int col = l & 15, quad = l >> 4;
        bf16x8 v;
#pragma unroll
        for (int j = 0; j < 8; ++j)
            v[j] = lds[col][ci * 32 + quad * 8 + j];
        *(bf16x8*)(o + ((size_t)s * nch + (c0 + ci)) * 512 + (size_t)l * 8) = v;
    }
}

// --------------------------- LDS-staged GEMM on packed weights, k-split
// Block: 512 thr = 8 waves, 16 o-strips (2/wave), all 160 m-rows. Per chunk
// the 32-k A-slice (10KB) is staged once into double-buffered LDS (1 barrier
// per chunk) and shared by all 8 waves. Partials -> part[blockIdx.y] via
// plain coalesced stores; consumers fold the SPL_-way sum.
template <int SW>
__global__ __launch_bounds__(512) void gemm_stage(
        const short* __restrict__ A, const short* __restrict__ Wp,
        const float* __restrict__ bias, float* __restrict__ part,
        int KpA, int nch, int O, int per) {
    int cs = blockIdx.y * per;
    int ce = min(nch, cs + per);
    if (cs >= ce) return;
    int tid = threadIdx.x;
    int lane = tid & 63, wave = tid >> 6;
    int col = lane & 15, quad = lane >> 4;
    int s0 = (blockIdx.x * 8 + wave) * SW;

    __shared__ short lbuf[2][160 * 32];          // 20 KB, double-buffered

    // staging map: segment = m*4+part (16B each); 640 segs, 512 threads
    int m0 = tid >> 2, p8 = (tid & 3) * 8;       // m 0..127
    int m1 = (tid + 512) >> 2;                   // m 128..159 for tid<128
    const short* a0 = A + (size_t)m0 * KpA + p8;
    const short* a1 = A + (size_t)m1 * KpA + p8;
    bf16x8 sr0, sr1;

    f32x4 acc[SW][10];
#pragma unroll
    for (int j = 0; j < SW; ++j)
#pragma unroll
        for (int t = 0; t < 10; ++t)
#pragma unroll
            for (int r = 0; r < 4; ++r) acc[j][t][r] = 0.f;

    const short* wbase[SW];
#pragma unroll
    for (int j = 0; j < SW; ++j)
        wbase[j] = Wp + (size_t)(s0 + j) * nch * 512 + (size_t)lane * 8;
    bf16x8 wc[SW], wn[SW];

    // prologue: stage chunk cs, preload W(cs)
    sr0 = *(const bf16x8*)(a0 + (size_t)cs * 32);
    if (tid < 128) sr1 = *(const bf16x8*)(a1 + (size_t)cs * 32);
#pragma unroll
    for (int j = 0; j < SW; ++j)
        wc[j] = *(const bf16x8*)(wbase[j] + (size_t)cs * 512);
    *(bf16x8*)(&lbuf[0][m0 * 32 + p8]) = sr0;
    if (tid < 128) *(bf16x8*)(&lbuf[0][m1 * 32 + p8]) = sr1;
    __syncthreads();

    int cur = 0;
    for (int c = cs; c < ce; ++c) {
        bool more = (c + 1) < ce;
        if (more) {                       // issue next-chunk loads early
            sr0 = *(const bf16x8*)(a0 + (size_t)(c + 1) * 32);
            if (tid < 128) sr1 = *(const bf16x8*)(a1 + (size_t)(c + 1) * 32);
#pragma unroll
            for (int j = 0; j < SW; ++j)
                wn[j] = *(const bf16x8*)(wbase[j] + (size_t)(c + 1) * 512);
        }
#pragma unroll
        for (int t = 0; t < 10; ++t) {
            bf16x8 af = *(const bf16x8*)(&lbuf[cur][t * 512 + col * 32 + quad * 8]);
#pragma unroll
            for (int j = 0; j < SW; ++j)
                acc[j][t] = __builtin_amdgcn_mfma_f32_16x16x32_bf16(af, wc[j], acc[j][t], 0, 0, 0);
        }
        if (more) {                       // other buffer: readers passed barrier
            *(bf16x8*)(&lbuf[cur ^ 1][m0 * 32 + p8]) = sr0;
            if (tid < 128) *(bf16x8*)(&lbuf[cur ^ 1][m1 * 32 + p8]) = sr1;
        }
        __syncthreads();
#pragma unroll
        for (int j = 0; j < SW; ++j) wc[j] = wn[j];
        cur ^= 1;
    }

    float* pout = part + (size_t)blockIdx.y * M_ * O;
#pragma unroll
    for (int j = 0; j < SW; ++j) {
        int oc = (s0 + j) * 16 + col;
        if (oc < O) {
            float bv = (blockIdx.y == 0) ? bias[oc] : 0.f;
#pragma unroll
            for (int t = 0; t < 10; ++t)
#pragma unroll
                for (int r = 0; r < 4; ++r)
                    pout[(size_t)(t * 16 + quad * 4 + r) * O + oc] = acc[j][t][r] + bv;
        }
    }
}

// ------------------------------------------------ MFMA GEMM, fp32 W (tier-0)
__global__ __launch_bounds__(256) void gemm_mfma_sk(
        const short* __restrict__ A, const float* __restrict__ Wf,
        const float* __restrict__ bias, float* __restrict__ Cout,
        int K, int KpA, int O, int KC) {
    int kc0 = blockIdx.y * KC;
    if (kc0 >= K) return;
    int kend = min(K, kc0 + KC);

    int lane = threadIdx.x & 63;
    int wave = threadIdx.x >> 6;
    int col  = lane & 15;
    int quad = lane >> 4;
    int o0 = blockIdx.x * 128 + wave * 32 + col;
    int o1 = o0 + 16;
    int oc0 = min(o0, O - 1), oc1 = min(o1, O - 1);

    const float* wrow0 = Wf + (size_t)oc0 * K + quad * 8;
    const float* wrow1 = Wf + (size_t)oc1 * K + quad * 8;
    const short* abase = A + (size_t)col * KpA + quad * 8;

    f32x4 acc0[10], acc1[10];
#pragma unroll
    for (int t = 0; t < 10; ++t)
#pragma unroll
        for (int r = 0; r < 4; ++r) { acc0[t][r] = 0.f; acc1[t][r] = 0.f; }

    int nfull = (kend - kc0) >> 5;
    bf16x8 aCur[10];
    float2 wCur[8];
    if (nfull > 0) {
#pragma unroll
        for (int t = 0; t < 10; ++t)
            aCur[t] = *(const bf16x8*)(abase + (size_t)t * 16 * KpA + kc0);
#pragma unroll
        for (int j = 0; j < 4; ++j) {
            wCur[j]     = *(const float2*)(wrow0 + kc0 + 2 * j);
            wCur[4 + j] = *(const float2*)(wrow1 + kc0 + 2 * j);
        }
    }
    for (int i = 0; i < nfull; ++i) {
        bf16x8 aNxt[10];
        float2 wNxt[8];
        if (i + 1 < nfull) {
            int kn = kc0 + (i + 1) * 32;
#pragma unroll
            for (int t = 0; t < 10; ++t)
                aNxt[t] = *(const bf16x8*)(abase + (size_t)t * 16 * KpA + kn);
#pragma unroll
            for (int j = 0; j < 4; ++j) {
                wNxt[j]     = *(const float2*)(wrow0 + kn + 2 * j);
                wNxt[4 + j] = *(const float2*)(wrow1 + kn + 2 * j);
            }
        }
        bf16x8 b0, b1;
#pragma unroll
        for (int j = 0; j < 4; ++j) {
            b0[2*j] = f2bf(wCur[j].x);     b0[2*j+1] = f2bf(wCur[j].y);
            b1[2*j] = f2bf(wCur[4+j].x);   b1[2*j+1] = f2bf(wCur[4+j].y);
        }
#pragma unroll
        for (int t = 0; t < 10; ++t) {
            acc0[t] = __builtin_amdgcn_mfma_f32_16x16x32_bf16(aCur[t], b0, acc0[t], 0, 0, 0);
            acc1[t] = __builtin_amdgcn_mfma_f32_16x16x32_bf16(aCur[t], b1, acc1[t], 0, 0, 0);
        }
#pragma unroll
        for (int t = 0; t < 10; ++t) aCur[t] = aNxt[t];
#pragma unroll
        for (int j = 0; j < 8; ++j) wCur[j] = wNxt[j];
    }
    int kmain = kc0 + nfull * 32;
    if (kmain < kend) {
        bf16x8 b0, b1;
#pragma unroll
        for (int j = 0; j < 8; ++j) {
            int k = kmain + quad * 8 + j;
            b0[j] = (k < kend) ? f2bf(Wf[(size_t)oc0 * K + k]) : (short)0;
            b1[j] = (k < kend) ? f2bf(Wf[(size_t)oc1 * K + k]) : (short)0;
        }
#pragma unroll
        for (int t = 0; t < 10; ++t) {
            bf16x8 af = *(const bf16x8*)(abase + (size_t)t * 16 * KpA + kmain);
            acc0[t] = __builtin_amdgcn_mfma_f32_16x16x32_bf16(af, b0, acc0[t], 0, 0, 0);
            acc1[t] = __builtin_amdgcn_mfma_f32_16x16x32_bf16(af, b1, acc1[t], 0, 0, 0);
        }
    }
    if (o0 < O) {
        float bv = (blockIdx.y == 0) ? bias[o0] : 0.f;
#pragma unroll
        for (int t = 0; t < 10; ++t)
#pragma unroll
            for (int r = 0; r < 4; ++r)
                atomicAdd(&Cout[(size_t)(t * 16 + quad * 4 + r) * O + o0], acc0[t][r] + bv);
    }
    if (o1 < O) {
        float bv = (blockIdx.y == 0) ? bias[o1] : 0.f;
#pragma unroll
        for (int t = 0; t < 10; ++t)
#pragma unroll
            for (int r = 0; r < 4; ++r)
                atomicAdd(&Cout[(size_t)(t * 16 + quad * 4 + r) * O + o1], acc1[t][r] + bv);
    }
}

// ------------------------------------ relu + bf16 convert (ff1), S-way fold
__global__ __launch_bounds__(256) void relu_cvt_kernel(const float* __restrict__ in,
                                                       int S, size_t sstr,
                                                       short* __restrict__ out,
                                                       int n) {
    int i = blockIdx.x * 256 + threadIdx.x;
    if (i < n) {
        float v = 0.f;
        for (int s = 0; s < S; ++s) v += in[(size_t)s * sstr + i];
        out[i] = f2bf(fmaxf(v, 0.f));
    }
}

// ------------------------------- qkv partials -> padded bf16 q/k/v, S-fold
__global__ __launch_bounds__(256) void qkv_cvt_kernel(const float* __restrict__ part,
                                                      int S,
                                                      short* __restrict__ q_bf,
                                                      short* __restrict__ k_bf,
                                                      short* __restrict__ v_bf) {
    int m = blockIdx.x;
    int b = m / N_, q = m % N_;
    for (int d = threadIdx.x; d < KPD_; d += 256) {
        short qv = 0, kv = 0, vv = 0;
        if (d < D_) {
            float qf = 0.f, kf = 0.f, vf = 0.f;
            for (int s = 0; s < S; ++s) {
                const float* p = part + (size_t)s * M_ * QKV_ + (size_t)m * QKV_;
                qf += p[d]; kf += p[D_ + d]; vf += p[2 * D_ + d];
            }
            qv = f2bf(qf); kv = f2bf(kf); vv = f2bf(vf);
        }
        q_bf[(size_t)m * KPD_ + d] = qv;
        k_bf[(size_t)m * KPD_ + d] = kv;
        v_bf[((size_t)b * 96 + q) * KPD_ + d] = vv;
    }
}

// ------------------------------------------------ scores = Q·K^T via MFMA
__global__ __launch_bounds__(256) void scores_mfma(const short* __restrict__ q_bf,
                                                   const short* __restrict__ k_bf,
                                                   float* __restrict__ sc) {
    int bi = blockIdx.x;
    int b = bi / 25, qt = (bi % 25) / 5, kt = bi % 5;
    int lane = threadIdx.x & 63, wave = threadIdx.x >> 6;
    int col = lane & 15, quad = lane >> 4;
    const short* qbase = q_bf + (size_t)(b * N_ + qt * 16 + col) * KPD_ + quad * 8;
    const short* kbase = k_bf + (size_t)(b * N_ + kt * 16 + col) * KPD_ + quad * 8;
    f32x4 acc;
#pragma unroll
    for (int r = 0; r < 4; ++r) acc[r] = 0.f;
    int c0 = wave * 25, c1 = min(97, c0 + 25);
    for (int c = c0; c < c1; ++c) {
        bf16x8 af = *(const bf16x8*)(qbase + c * 32);
        bf16x8 bf8 = *(const bf16x8*)(kbase + c * 32);
        acc = __builtin_amdgcn_mfma_f32_16x16x32_bf16(af, bf8, acc, 0, 0, 0);
    }
    __shared__ f32x4 red[4][64];
    red[wave][lane] = acc;
    __syncthreads();
    if (threadIdx.x < 64) {
        f32x4 t = red[0][lane];
#pragma unroll
        for (int w = 1; w < 4; ++w)
#pragma unroll
            for (int r = 0; r < 4; ++r) t[r] += red[w][lane][r];
        float scale = rsqrtf((float)D_);
#pragma unroll
        for (int r = 0; r < 4; ++r)
            sc[(size_t)(b * N_ + qt * 16 + quad * 4 + r) * N_ + kt * 16 + col] = t[r] * scale;
    }
}

// ------------------------------------------------ softmax -> p_bf [M_][96]
__global__ __launch_bounds__(256) void softmax_kernel(const float* __restrict__ sc,
                                                      short* __restrict__ p_bf) {
    int m = blockIdx.x * 4 + (threadIdx.x >> 6);
    int lane = threadIdx.x & 63;
    const float* row = sc + (size_t)m * N_;
    float a = row[lane];
    float bv = (lane < 16) ? row[64 + lane] : -1e30f;
    float mx = wave_max(fmaxf(a, bv));
    mx = __shfl(mx, 0, 64);
    float e0 = expf(a - mx);
    float e1 = (lane < 16) ? expf(bv - mx) : 0.f;
    float sum = wave_sum(e0 + e1);
    sum = __shfl(sum, 0, 64);
    float rs = 1.0f / sum;
    p_bf[(size_t)m * 96 + lane] = f2bf(e0 * rs);
    if (lane < 32)
        p_bf[(size_t)m * 96 + 64 + lane] = (lane < 16) ? f2bf(e1 * rs) : (short)0;
}

// ------------------------------------------------ av = P·V via MFMA
__global__ __launch_bounds__(256) void av_mfma(const short* __restrict__ p_bf,
                                               const short* __restrict__ v_bf,
                                               short* __restrict__ av_bf) {
    int bi = blockIdx.x;
    int b = bi / 49, g = bi % 49;
    int lane = threadIdx.x & 63, wave = threadIdx.x >> 6;
    int dtile = g * 4 + wave;
    if (dtile >= 194) return;
    int d0 = dtile * 16;
    int col = lane & 15, quad = lane >> 4;
    const short* pbase = p_bf + (size_t)b * N_ * 96 + quad * 8;
    const short* vb = v_bf + (size_t)b * 96 * KPD_ + d0 + col;
    f32x4 acc[5];
#pragma unroll
    for (int t = 0; t < 5; ++t)
#pragma unroll
        for (int r = 0; r < 4; ++r) acc[t][r] = 0.f;
#pragma unroll
    for (int c = 0; c < 3; ++c) {
        bf16x8 bf8;
#pragma unroll
        for (int j = 0; j < 8; ++j)
            bf8[j] = vb[(size_t)(c * 32 + quad * 8 + j) * KPD_];
#pragma unroll
        for (int t = 0; t < 5; ++t) {
            bf16x8 af = *(const bf16x8*)(pbase + (size_t)(t * 16 + col) * 96 + c * 32);
            acc[t] = __builtin_amdgcn_mfma_f32_16x16x32_bf16(af, bf8, acc[t], 0, 0, 0);
        }
    }
#pragma unroll
    for (int t = 0; t < 5; ++t)
#pragma unroll
        for (int r = 0; r < 4; ++r)
            av_bf[(size_t)(b * N_ + t * 16 + quad * 4 + r) * KPD_ + d0 + col] = f2bf(acc[t][r]);
}

// ------------------------------------------- layernorm, S-way partial fold
template <bool WF32>
__global__ __launch_bounds__(256) void ln_kernel(const float* __restrict__ xin,
                                                 int S, size_t sstr,
                                                 const float* __restrict__ res,
                                                 const float* __restrict__ g,
                                                 const float* __restrict__ bta,
                                                 float* __restrict__ outf,
                                                 short* __restrict__ outb) {
    int m = blockIdx.x;
    int tid = threadIdx.x;
    __shared__ float red[10];
    const float* xr = xin + (size_t)m * D_;
    const float* rr = res + (size_t)m * D_;
    float vv[13];
    float s = 0.f, s2 = 0.f;
#pragma unroll
    for (int i = 0; i < 13; ++i) {
        int d = tid + i * 256;
        float v = 0.f;
        if (d < D_) {
            v = rr[d];
            for (int sp = 0; sp < S; ++sp) v += xr[(size_t)sp * sstr + d];
            s += v; s2 += v * v;
        }
        vv[i] = v;
    }
    block_reduce_2(s, s2, red);
    float mean = s / (float)D_;
    float var = s2 / (float)D_ - mean * mean;
    float inv = rsqrtf(var + EPS_);
#pragma unroll
    for (int i = 0; i < 13; ++i) {
        int d = tid + i * 256;
        if (d < D_) {
            float y = g[d] * (vv[i] - mean) * inv + bta[d];
            if (WF32) outf[(size_t)m * D_ + d] = y;
            outb[(size_t)m * KPD_ + d] = f2bf(y);
        } else if (d < KPD_) {
            outb[(size_t)m * KPD_ + d] = 0;
        }
    }
}

// ---------------------------------------------------------------- update
__global__ __launch_bounds__(256) void update_kernel(const float* __restrict__ part,
                                                     int S, size_t sstr,
                                                     float* __restrict__ curr,
                                                     float* __restrict__ pre_q,
                                                     float* __restrict__ results) {
    int m = blockIdx.x;
    int tid = threadIdx.x;
    const float* pr = part + (size_t)m * OD_;
    for (int c = tid; c < C_; c += 256) {
        float v = 0.f;
        for (int s = 0; s < S; ++s) v += pr[(size_t)s * sstr + c];
        pre_q[(size_t)m * C_ + c] += v;
    }
    if (tid < 2) {
        float v = 0.f;
        for (int s = 0; s < S; ++s) v += pr[(size_t)s * sstr + C_ + tid];
        float nc = curr[m * 2 + tid] + v;
        nc = fminf(fmaxf(nc, 0.f), 223.f);
        curr[m * 2 + tid] = nc;
        results[m * 2 + tid] = nc;
    }
}

// ---------------------------------------------------------------- launch
extern "C" void kernel_launch(void* const* d_in, const int* in_sizes, int n_in,
                              void* d_out, int out_size, void* d_ws, size_t ws_size,
                              hipStream_t stream) {
    const float* pre_f   = (const float*)d_in[0];
    const float* curr_f  = (const float*)d_in[1];
    const float* first_f = (const float*)d_in[2];
    const int*   prev_b  = (const int*)d_in[3];
    const int*   first_b = (const int*)d_in[4];
    const float* ln_g    = (const float*)d_in[5];
    const float* ln_b    = (const float*)d_in[6];
    const float* ipw     = (const float*)d_in[7];
    const float* ipb     = (const float*)d_in[8];
    const float* opw     = (const float*)d_in[9];
    const float* opb     = (const float*)d_in[10];
    const float* n1g     = (const float*)d_in[11];
    const float* n1b     = (const float*)d_in[12];
    const float* l1w     = (const float*)d_in[13];
    const float* l1b     = (const float*)d_in[14];
    const float* l2w     = (const float*)d_in[15];
    const float* l2b     = (const float*)d_in[16];
    const float* n2g     = (const float*)d_in[17];
    const float* n2b     = (const float*)d_in[18];
    const float* ow      = (const float*)d_in[19];
    const float* ob      = (const float*)d_in[20];
    float* outp = (float*)d_out;

    float* wf = (float*)d_ws;
    size_t off = 0;
    // ---- common buffers
    int*   fb_al   = (int*)(wf + off); off += 320;
    float* curr    = wf + off;         off += 320;
    float* pre_q   = wf + off;         off += (size_t)M_ * C_;
    float* first_q = wf + off;         off += (size_t)M_ * C_;
    float* tokens  = wf + off;         off += (size_t)M_ * D_;
    float* xbuf    = wf + off;         off += (size_t)M_ * D_;
    float* sc      = wf + off;         off += (size_t)M_ * N_;
    float* pe_tab  = wf + off;         off += (size_t)N_ * D_;
    short* tokens_bf = (short*)(wf + off); off += (size_t)M_ * KPD_ / 2;
    short* x_bf      = (short*)(wf + off); off += (size_t)M_ * KPD_ / 2;
    short* x2_bf     = (short*)(wf + off); off += (size_t)M_ * KPD_ / 2;
    short* av_bf     = (short*)(wf + off); off += (size_t)M_ * KPD_ / 2;
    short* ff1_bf    = (short*)(wf + off); off += (size_t)M_ * DFF_ / 2;
    short* q_bf      = (short*)(wf + off); off += (size_t)M_ * KPD_ / 2;
    short* k_bf      = (short*)(wf + off); off += (size_t)M_ * KPD_ / 2;
    short* v_bf      = (short*)(wf + off); off += (size_t)B_ * 96 * KPD_ / 2;
    short* p_bf      = (short*)(wf + off); off += (size_t)M_ * 96 / 2;
    size_t commonF = off;

    // ---- tier-2: packed weights (strips padded to x16 groups) + partials
    // groups: qkv 37(592), op 13(208), ff1 8(128), ff2 13(208), head 5(80)
    size_t o2 = commonF;
    short* ipw_p2 = (short*)(wf + o2); o2 += (size_t)592 * 97 * 256;
    short* opw_p2 = (short*)(wf + o2); o2 += (size_t)208 * 97 * 256;
    short* l1w_p2 = (short*)(wf + o2); o2 += (size_t)128 * 97 * 256;
    short* l2w_p2 = (short*)(wf + o2); o2 += (size_t)208 * 64 * 256;
    short* ow_p2  = (short*)(wf + o2); o2 += (size_t)80  * 97 * 256;
    float* gpart  = wf + o2;           o2 += (size_t)SPL_ * M_ * QKV_;

    // ---- tier-0: fp32 GEMM outs (fallback)
    size_t o0 = commonF;
    float* qkv   = wf + o0; o0 += (size_t)M_ * QKV_;
    float* aout  = wf + o0; o0 += (size_t)M_ * D_;
    float* ff1f  = wf + o0; o0 += (size_t)M_ * DFF_;
    float* ffout = wf + o0; o0 += (size_t)M_ * D_;
    float* outb  = wf + o0; o0 += (size_t)M_ * OD_;

    int tier = (ws_size >= o2 * sizeof(float)) ? 2 : 0;
    (void)in_sizes; (void)n_in; (void)out_size;

    hipLaunchKernelGGL(align_kernel, dim3(B_), dim3(128), 0, stream,
                       prev_b, first_b, fb_al);
    hipLaunchKernelGGL(gather_init_kernel, dim3(M_), dim3(256), 0, stream,
                       pre_f, first_f, prev_b, fb_al, pre_q, first_q, curr);
    hipLaunchKernelGGL(pe_kernel, dim3(N_), dim3(256), 0, stream, pe_tab);
    hipMemsetAsync(v_bf, 0, (size_t)B_ * 96 * KPD_ * 2, stream);

    if (tier == 2) {
        hipLaunchKernelGGL(wpack_kernel, dim3(592, 4), dim3(256), 0, stream, ipw, ipw_p2, D_, QKV_, 97);
        hipLaunchKernelGGL(wpack_kernel, dim3(208, 4), dim3(256), 0, stream, opw, opw_p2, D_, D_, 97);
        hipLaunchKernelGGL(wpack_kernel, dim3(128, 4), dim3(256), 0, stream, l1w, l1w_p2, D_, DFF_, 97);
        hipLaunchKernelGGL(wpack_kernel, dim3(208, 4), dim3(256), 0, stream, l2w, l2w_p2, DFF_, D_, 64);
        hipLaunchKernelGGL(wpack_kernel, dim3(80, 4),  dim3(256), 0, stream, ow, ow_p2, D_, OD_, 97);
    }

    for (int it = 0; it < 3; ++it) {
        if (tier == 0) {
            hipMemsetAsync(qkv,   0, (size_t)M_ * QKV_ * 4, stream);
            hipMemsetAsync(aout,  0, (size_t)M_ * D_   * 4, stream);
            hipMemsetAsync(ff1f,  0, (size_t)M_ * DFF_ * 4, stream);
            hipMemsetAsync(ffout, 0, (size_t)M_ * D_   * 4, stream);
            hipMemsetAsync(outb,  0, (size_t)M_ * OD_  * 4, stream);
        }

        hipLaunchKernelGGL(tokens_kernel, dim3(M_), dim3(256), 0, stream,
                           curr_f, pre_q, first_q, curr, ln_g, ln_b, pe_tab,
                           tokens, tokens_bf);
        // ---------------- qkv
        if (tier == 2)
            hipLaunchKernelGGL((gemm_stage<2>), dim3(37, SPL_), dim3(512), 0, stream,
                               tokens_bf, ipw_p2, ipb, gpart, KPD_, 97, QKV_, 25);
        else
            hipLaunchKernelGGL(gemm_mfma_sk, dim3(73, 6), dim3(256), 0, stream,
                               tokens_bf, ipw, ipb, qkv, D_, KPD_, QKV_, 544);
        hipLaunchKernelGGL(qkv_cvt_kernel, dim3(M_), dim3(256), 0, stream,
                           (tier == 2) ? gpart : qkv, (tier == 2) ? SPL_ : 1,
                           q_bf, k_bf, v_bf);
        hipLaunchKernelGGL(scores_mfma, dim3(50), dim3(256), 0, stream,
                           q_bf, k_bf, sc);
        hipLaunchKernelGGL(softmax_kernel, dim3(40), dim3(256), 0, stream,
                           sc, p_bf);
        hipLaunchKernelGGL(av_mfma, dim3(98), dim3(256), 0, stream,
                           p_bf, v_bf, av_bf);
        // ---------------- out-proj
        if (tier == 2)
            hipLaunchKernelGGL((gemm_stage<2>), dim3(13, SPL_), dim3(512), 0, stream,
                               av_bf, opw_p2, opb, gpart, KPD_, 97, D_, 25);
        else
            hipLaunchKernelGGL(gemm_mfma_sk, dim3(25, 10), dim3(256), 0, stream,
                               av_bf, opw, opb, aout, D_, KPD_, D_, 320);
        hipLaunchKernelGGL((ln_kernel<true>), dim3(M_), dim3(256), 0, stream,
                           (tier == 2) ? gpart : aout, (tier == 2) ? SPL_ : 1, (size_t)M_ * D_,
                           tokens, n1g, n1b, xbuf, x_bf);
        // ---------------- ff1
        if (tier == 2)
            hipLaunchKernelGGL((gemm_stage<2>), dim3(8, SPL_), dim3(512), 0, stream,
                               x_bf, l1w_p2, l1b, gpart, KPD_, 97, DFF_, 25);
        else
            hipLaunchKernelGGL(gemm_mfma_sk, dim3(16, 17), dim3(256), 0, stream,
                               x_bf, l1w, l1b, ff1f, D_, KPD_, DFF_, 192);
        hipLaunchKernelGGL(relu_cvt_kernel, dim3((M_ * DFF_ + 255) / 256), dim3(256), 0, stream,
                           (tier == 2) ? gpart : ff1f, (tier == 2) ? SPL_ : 1, (size_t)M_ * DFF_,
                           ff1_bf, M_ * DFF_);
        // ---------------- ff2
        if (tier == 2)
            hipLaunchKernelGGL((gemm_stage<2>), dim3(13, SPL_), dim3(512), 0, stream,
                               ff1_bf, l2w_p2, l2b, gpart, DFF_, 64, D_, 16);
        else
            hipLaunchKernelGGL(gemm_mfma_sk, dim3(25, 11), dim3(256), 0, stream,
                               ff1_bf, l2w, l2b, ffout, DFF_, DFF_, D_, 192);
        hipLaunchKernelGGL((ln_kernel<false>), dim3(M_), dim3(256), 0, stream,
                           (tier == 2) ? gpart : ffout, (tier == 2) ? SPL_ : 1, (size_t)M_ * D_,
                           xbuf, n2g, n2b, (float*)nullptr, x2_bf);
        // ---------------- head
        if (tier == 2)
            hipLaunchKernelGGL((gemm_stage<2>), dim3(5, SPL_), dim3(512), 0, stream,
                               x2_bf, ow_p2, ob, gpart, KPD_, 97, OD_, 25);
        else
            hipLaunchKernelGGL(gemm_mfma_sk, dim3(9, 13), dim3(256), 0, stream,
                               x2_bf, ow, ob, outb, D_, KPD_, OD_, 256);
        hipLaunchKernelGGL(update_kernel, dim3(M_), dim3(256), 0, stream,
                           (tier == 2) ? gpart : outb, (tier == 2) ? SPL_ : 1, (size_t)M_ * OD_,
                           curr, pre_q, outp + (size_t)it * M_ * 2);
    }
}

// Round 5
// 1021.839 us; speedup vs baseline: 1.1093x; 1.0667x over previous
//
#include <hip/hip_runtime.h>
#include <math.h>

#define B_    2
#define C_    1024
#define N_    80
#define D_    3074
#define DFF_  2048
#define OD_   1026      // C+2
#define QKV_  9222      // 3*D
#define M_    160       // B*N token rows
#define EPS_  1e-5f
#define KPD_  3104      // D_ rounded up to multiple of 32 (bf16 row stride)

// split-K (S, per): per*S >= nch, last split non-empty
#define SQKV 4
#define PQKV 25
#define SOP  8
#define POP  13
#define SFF1 11
#define PFF1 9
#define SFF2 8
#define PFF2 8
#define SHD  11
#define PHD  9

typedef __attribute__((ext_vector_type(8))) short bf16x8;   // 8 bf16 = 4 VGPRs
typedef __attribute__((ext_vector_type(4))) float f32x4;

// fp32 -> bf16 (round-to-nearest-even), bit pattern as short
__device__ inline short f2bf(float f) {
    unsigned u = __float_as_uint(f);
    u += 0x7fffu + ((u >> 16) & 1u);
    return (short)(u >> 16);
}

__device__ inline int pack2bf(float lo, float hi) {
    return (int)(unsigned short)f2bf(lo) | ((int)(unsigned short)f2bf(hi) << 16);
}

// ---------------------------------------------------------------- reductions
__device__ inline float wave_sum(float v) {
#pragma unroll
    for (int off = 32; off > 0; off >>= 1) v += __shfl_down(v, off, 64);
    return v;
}

__device__ inline void block_reduce_2(float& s, float& s2, float* red) {
    int tid = threadIdx.x;
    int lane = tid & 63, wid = tid >> 6;
    s = wave_sum(s);
    s2 = wave_sum(s2);
    if (lane == 0) { red[wid] = s; red[4 + wid] = s2; }
    __syncthreads();
    if (tid == 0) {
        red[8] = red[0] + red[1] + red[2] + red[3];
        red[9] = red[4] + red[5] + red[6] + red[7];
    }
    __syncthreads();
    s = red[8]; s2 = red[9];
}

// ---------------------------------------------------------------- bilinear
__device__ inline void bilin_setup(int p, int& i0, int& i1, float& t) {
    float s = (p + 0.5f) * 0.0625f - 0.5f;
    s = fminf(fmaxf(s, 0.0f), 13.0f);
    i0 = (int)s;
    t = s - (float)i0;
    i1 = min(i0 + 1, 13);
}

__device__ inline float bilin_tap(const float* f, int y0, int y1, float ty,
                                  int x0, int x1, float tx) {
    float a = f[y0 * 14 + x0], b = f[y0 * 14 + x1];
    float c = f[y1 * 14 + x0], d = f[y1 * 14 + x1];
    return (1.f - ty) * ((1.f - tx) * a + tx * b) + ty * ((1.f - tx) * c + tx * d);
}

// ---------------------------------------------------------------- K0: align
__global__ __launch_bounds__(128) void align_kernel(const int* __restrict__ prev_b,
                                                    const int* __restrict__ first_b,
                                                    int* __restrict__ fb_al) {
    int b = blockIdx.x;
    int tid = threadIdx.x;
    __shared__ int dist[N_];
    __shared__ int bestIdx;
    if (tid < N_) {
        int s = 0;
        for (int j = 0; j < N_; ++j) {
            int src = (j - tid) % N_;
            if (src < 0) src += N_;
            int dy = prev_b[(b * N_ + j) * 2] - first_b[(b * N_ + src) * 2];
            int dx = prev_b[(b * N_ + j) * 2 + 1] - first_b[(b * N_ + src) * 2 + 1];
            s += abs(dy) + abs(dx);
        }
        dist[tid] = s;
    }
    __syncthreads();
    if (tid == 0) {
        int best = 0, bd = dist[0];
        for (int i = 1; i < N_; ++i)
            if (dist[i] < bd) { bd = dist[i]; best = i; }
        bestIdx = best;
    }
    __syncthreads();
    if (tid < N_) {
        int src = (tid - bestIdx) % N_;
        if (src < 0) src += N_;
        fb_al[(b * N_ + tid) * 2]     = first_b[(b * N_ + src) * 2];
        fb_al[(b * N_ + tid) * 2 + 1] = first_b[(b * N_ + src) * 2 + 1];
    }
}

// -------------------------------------------------- K1: pre_q/first_q gather
__global__ __launch_bounds__(256) void gather_init_kernel(
        const float* __restrict__ pre_f, const float* __restrict__ first_f,
        const int* __restrict__ prev_b, const int* __restrict__ fb_al,
        float* __restrict__ pre_q, float* __restrict__ first_q,
        float* __restrict__ curr) {
    int m = blockIdx.x;
    int b = m / N_;
    int tid = threadIdx.x;
    int py = prev_b[m * 2], px = prev_b[m * 2 + 1];
    int fy = fb_al[m * 2], fx = fb_al[m * 2 + 1];
    int py0, py1, px0, px1, fy0, fy1, fx0, fx1;
    float pty, ptx, fty, ftx;
    bilin_setup(py, py0, py1, pty);
    bilin_setup(px, px0, px1, ptx);
    bilin_setup(fy, fy0, fy1, fty);
    bilin_setup(fx, fx0, fx1, ftx);
    for (int c = tid; c < C_; c += 256) {
        const float* fp = pre_f + (size_t)(b * C_ + c) * 196;
        const float* ff = first_f + (size_t)(b * C_ + c) * 196;
        pre_q[(size_t)m * C_ + c]   = bilin_tap(fp, py0, py1, pty, px0, px1, ptx);
        first_q[(size_t)m * C_ + c] = bilin_tap(ff, fy0, fy1, fty, fx0, fx1, ftx);
    }
    if (tid < 2) curr[m * 2 + tid] = (float)prev_b[m * 2 + tid];
}

// ----------------------------------------------- positional-encoding table
__global__ __launch_bounds__(256) void pe_kernel(float* __restrict__ pe) {
    int n = blockIdx.x;
    const float negLogDivD = -logf(10000.0f) / (float)D_;
    for (int d = threadIdx.x; d < D_; d += 256) {
        int kk = d >> 1;
        float ang = (float)n * expf((float)(2 * kk) * negLogDivD);
        pe[(size_t)n * D_ + d] = (d & 1) ? cosf(ang) : sinf(ang);
    }
}

// -------------------------------------------------- K2: tokens = LN(cat)+pe
__global__ __launch_bounds__(256) void tokens_kernel(
        const float* __restrict__ curr_f, const float* __restrict__ pre_q,
        const float* __restrict__ first_q, const float* __restrict__ curr,
        const float* __restrict__ ln_g, const float* __restrict__ ln_b,
        const float* __restrict__ pe_tab,
        float* __restrict__ tokens, short* __restrict__ tokens_bf) {
    int m = blockIdx.x;
    int b = m / N_;
    int n = m % N_;
    int tid = threadIdx.x;
    __shared__ float bf[C_];
    __shared__ float red[10];

    float cy = curr[m * 2], cx = curr[m * 2 + 1];
    int iy = (int)cy, ix = (int)cx;
    int y0, y1, x0, x1;
    float ty, tx;
    bilin_setup(iy, y0, y1, ty);
    bilin_setup(ix, x0, x1, tx);
    for (int c = tid; c < C_; c += 256) {
        const float* f = curr_f + (size_t)(b * C_ + c) * 196;
        bf[c] = bilin_tap(f, y0, y1, ty, x0, x1, tx);
    }
    __syncthreads();

    float s = 0.f, s2 = 0.f;
    for (int d = tid; d < D_; d += 256) {
        float v;
        if (d < C_)            v = pre_q[(size_t)m * C_ + d];
        else if (d < 2 * C_)   v = bf[d - C_];
        else if (d == 2 * C_)  v = cy;
        else if (d == 2*C_+1)  v = cx;
        else                   v = first_q[(size_t)m * C_ + (d - 2 * C_ - 2)];
        s += v; s2 += v * v;
    }
    block_reduce_2(s, s2, red);
    float mean = s / (float)D_;
    float var = s2 / (float)D_ - mean * mean;
    float inv = rsqrtf(var + EPS_);

    for (int d = tid; d < KPD_; d += 256) {
        if (d < D_) {
            float v;
            if (d < C_)            v = pre_q[(size_t)m * C_ + d];
            else if (d < 2 * C_)   v = bf[d - C_];
            else if (d == 2 * C_)  v = cy;
            else if (d == 2*C_+1)  v = cx;
            else                   v = first_q[(size_t)m * C_ + (d - 2 * C_ - 2)];
            float ln = ln_g[d] * (v - mean) * inv + ln_b[d];
            float val = ln + pe_tab[(size_t)n * D_ + d];
            tokens[(size_t)m * D_ + d] = val;
            tokens_bf[(size_t)m * KPD_ + d] = f2bf(val);
        } else {
            tokens_bf[(size_t)m * KPD_ + d] = 0;
        }
    }
}

// ---------------------- weight fp32 -> fragment-packed bf16, wave-per-tile
// Target: Wp[(tile)*512 + l*8 + j] = W[strip*16+(l&15)][chunk*32+(l>>4)*8+j].
// The pack is a pure 16B lane permutation: out lane l = in lane (l&15)*4+(l>>4).
// Read coalesced (lane l: row strip*16+(l>>2), 32B), pack, 4x shfl, 16B store.
__global__ __launch_bounds__(256) void wpack2(const float* __restrict__ w,
                                              short* __restrict__ o,
                                              int K, int O, int nch, int ntiles) {
    int gw = (int)((blockIdx.x * 256 + threadIdx.x) >> 6);
    if (gw >= ntiles) return;
    int lane = threadIdx.x & 63;
    int strip = gw / nch, chunk = gw - strip * nch;
    int row = strip * 16 + (lane >> 2);
    int k0 = chunk * 32 + (lane & 3) * 8;
    float f[8];
    if (row < O && k0 + 8 <= K) {
        const float* src = w + (size_t)row * K + k0;
        float2 a = *(const float2*)(src);
        float2 b = *(const float2*)(src + 2);
        float2 c = *(const float2*)(src + 4);
        float2 d = *(const float2*)(src + 6);
        f[0]=a.x; f[1]=a.y; f[2]=b.x; f[3]=b.y;
        f[4]=c.x; f[5]=c.y; f[6]=d.x; f[7]=d.y;
    } else {
#pragma unroll
        for (int j = 0; j < 8; ++j) {
            int k = k0 + j;
            f[j] = (row < O && k < K) ? w[(size_t)row * K + k] : 0.f;
        }
    }
    int p0 = pack2bf(f[0], f[1]);
    int p1 = pack2bf(f[2], f[3]);
    int p2 = pack2bf(f[4], f[5]);
    int p3 = pack2bf(f[6], f[7]);
    int src = (lane & 15) * 4 + (lane >> 4);
    int4 out;
    out.x = __shfl(p0, src, 64);
    out.y = __shfl(p1, src, 64);
    out.z = __shfl(p2, src, 64);
    out.w = __shfl(p3, src, 64);
    *(int4*)(o + (size_t)gw * 512 + (size_t)lane * 8) = out;
}

// --------------------------- LDS-staged GEMM on packed weights, k-split
// Block: 512 thr = 8 waves, 16 o-strips (2/wave), all 160 m-rows. Per chunk
// the 32-k A-slice (10KB) is staged once into double-buffered LDS (1 barrier
// per chunk) and shared by all 8 waves. Partials -> part[blockIdx.y] via
// plain coalesced stores; consumers fold the S-way sum.
template <int SW>
__global__ __launch_bounds__(512) void gemm_stage(
        const short* __restrict__ A, const short* __restrict__ Wp,
        const float* __restrict__ bias, float* __restrict__ part,
        int KpA, int nch, int O, int per) {
    int cs = blockIdx.y * per;
    int ce = min(nch, cs + per);
    if (cs >= ce) return;
    int tid = threadIdx.x;
    int lane = tid & 63, wave = tid >> 6;
    int col = lane & 15, quad = lane >> 4;
    int s0 = (blockIdx.x * 8 + wave) * SW;

    __shared__ short lbuf[2][160 * 32];          // 20 KB, double-buffered

    // staging map: segment = m*4+part (16B each); 640 segs, 512 threads
    int m0 = tid >> 2, p8 = (tid & 3) * 8;       // m 0..127
    int m1 = (tid + 512) >> 2;                   // m 128..159 for tid<128
    const short* a0 = A + (size_t)m0 * KpA + p8;
    const short* a1 = A + (size_t)m1 * KpA + p8;
    bf16x8 sr0, sr1;

    f32x4 acc[SW][10];
#pragma unroll
    for (int j = 0; j < SW; ++j)
#pragma unroll
        for (int t = 0; t < 10; ++t)
#pragma unroll
            for (int r = 0; r < 4; ++r) acc[j][t][r] = 0.f;

    const short* wbase[SW];
#pragma unroll
    for (int j = 0; j < SW; ++j)
        wbase[j] = Wp + (size_t)(s0 + j) * nch * 512 + (size_t)lane * 8;
    bf16x8 wc[SW], wn[SW];

    // prologue: stage chunk cs, preload W(cs)
    sr0 = *(const bf16x8*)(a0 + (size_t)cs * 32);
    if (tid < 128) sr1 = *(const bf16x8*)(a1 + (size_t)cs * 32);
#pragma unroll
    for (int j = 0; j < SW; ++j)
        wc[j] = *(const bf16x8*)(wbase[j] + (size_t)cs * 512);
    *(bf16x8*)(&lbuf[0][m0 * 32 + p8]) = sr0;
    if (tid < 128) *(bf16x8*)(&lbuf[0][m1 * 32 + p8]) = sr1;
    __syncthreads();

    int cur = 0;
    for (int c = cs; c < ce; ++c) {
        bool more = (c + 1) < ce;
        if (more) {                       // issue next-chunk loads early
            sr0 = *(const bf16x8*)(a0 + (size_t)(c + 1) * 32);
            if (tid < 128) sr1 = *(const bf16x8*)(a1 + (size_t)(c + 1) * 32);
#pragma unroll
            for (int j = 0; j < SW; ++j)
                wn[j] = *(const bf16x8*)(wbase[j] + (size_t)(c + 1) * 512);
        }
#pragma unroll
        for (int t = 0; t < 10; ++t) {
            bf16x8 af = *(const bf16x8*)(&lbuf[cur][t * 512 + col * 32 + quad * 8]);
#pragma unroll
            for (int j = 0; j < SW; ++j)
                acc[j][t] = __builtin_amdgcn_mfma_f32_16x16x32_bf16(af, wc[j], acc[j][t], 0, 0, 0);
        }
        if (more) {                       // other buffer: readers passed barrier
            *(bf16x8*)(&lbuf[cur ^ 1][m0 * 32 + p8]) = sr0;
            if (tid < 128) *(bf16x8*)(&lbuf[cur ^ 1][m1 * 32 + p8]) = sr1;
        }
        __syncthreads();
#pragma unroll
        for (int j = 0; j < SW; ++j) wc[j] = wn[j];
        cur ^= 1;
    }

    float* pout = part + (size_t)blockIdx.y * M_ * O;
#pragma unroll
    for (int j = 0; j < SW; ++j) {
        int oc = (s0 + j) * 16 + col;
        if (oc < O) {
            float bv = (blockIdx.y == 0) ? bias[oc] : 0.f;
#pragma unroll
            for (int t = 0; t < 10; ++t)
#pragma unroll
                for (int r = 0; r < 4; ++r)
                    pout[(size_t)(t * 16 + quad * 4 + r) * O + oc] = acc[j][t][r] + bv;
        }
    }
}

// ------------------------------------------------ MFMA GEMM, fp32 W (tier-0)
__global__ __launch_bounds__(256) void gemm_mfma_sk(
        const short* __restrict__ A, const float* __restrict__ Wf,
        const float* __restrict__ bias, float* __restrict__ Cout,
        int K, int KpA, int O, int KC) {
    int kc0 = blockIdx.y * KC;
    if (kc0 >= K) return;
    int kend = min(K, kc0 + KC);

    int lane = threadIdx.x & 63;
    int wave = threadIdx.x >> 6;
    int col  = lane & 15;
    int quad = lane >> 4;
    int o0 = blockIdx.x * 128 + wave * 32 + col;
    int o1 = o0 + 16;
    int oc0 = min(o0, O - 1), oc1 = min(o1, O - 1);

    const float* wrow0 = Wf + (size_t)oc0 * K + quad * 8;
    const float* wrow1 = Wf + (size_t)oc1 * K + quad * 8;
    const short* abase = A + (size_t)col * KpA + quad * 8;

    f32x4 acc0[10], acc1[10];
#pragma unroll
    for (int t = 0; t < 10; ++t)
#pragma unroll
        for (int r = 0; r < 4; ++r) { acc0[t][r] = 0.f; acc1[t][r] = 0.f; }

    int nfull = (kend - kc0) >> 5;
    bf16x8 aCur[10];
    float2 wCur[8];
    if (nfull > 0) {
#pragma unroll
        for (int t = 0; t < 10; ++t)
            aCur[t] = *(const bf16x8*)(abase + (size_t)t * 16 * KpA + kc0);
#pragma unroll
        for (int j = 0; j < 4; ++j) {
            wCur[j]     = *(const float2*)(wrow0 + kc0 + 2 * j);
            wCur[4 + j] = *(const float2*)(wrow1 + kc0 + 2 * j);
        }
    }
    for (int i = 0; i < nfull; ++i) {
        bf16x8 aNxt[10];
        float2 wNxt[8];
        if (i + 1 < nfull) {
            int kn = kc0 + (i + 1) * 32;
#pragma unroll
            for (int t = 0; t < 10; ++t)
                aNxt[t] = *(const bf16x8*)(abase + (size_t)t * 16 * KpA + kn);
#pragma unroll
            for (int j = 0; j < 4; ++j) {
                wNxt[j]     = *(const float2*)(wrow0 + kn + 2 * j);
                wNxt[4 + j] = *(const float2*)(wrow1 + kn + 2 * j);
            }
        }
        bf16x8 b0, b1;
#pragma unroll
        for (int j = 0; j < 4; ++j) {
            b0[2*j] = f2bf(wCur[j].x);     b0[2*j+1] = f2bf(wCur[j].y);
            b1[2*j] = f2bf(wCur[4+j].x);   b1[2*j+1] = f2bf(wCur[4+j].y);
        }
#pragma unroll
        for (int t = 0; t < 10; ++t) {
            acc0[t] = __builtin_amdgcn_mfma_f32_16x16x32_bf16(aCur[t], b0, acc0[t], 0, 0, 0);
            acc1[t] = __builtin_amdgcn_mfma_f32_16x16x32_bf16(aCur[t], b1, acc1[t], 0, 0, 0);
        }
#pragma unroll
        for (int t = 0; t < 10; ++t) aCur[t] = aNxt[t];
#pragma unroll
        for (int j = 0; j < 8; ++j) wCur[j] = wNxt[j];
    }
    int kmain = kc0 + nfull * 32;
    if (kmain < kend) {
        bf16x8 b0, b1;
#pragma unroll
        for (int j = 0; j < 8; ++j) {
            int k = kmain + quad * 8 + j;
            b0[j] = (k < kend) ? f2bf(Wf[(size_t)oc0 * K + k]) : (short)0;
            b1[j] = (k < kend) ? f2bf(Wf[(size_t)oc1 * K + k]) : (short)0;
        }
#pragma unroll
        for (int t = 0; t < 10; ++t) {
            bf16x8 af = *(const bf16x8*)(abase + (size_t)t * 16 * KpA + kmain);
            acc0[t] = __builtin_amdgcn_mfma_f32_16x16x32_bf16(af, b0, acc0[t], 0, 0, 0);
            acc1[t] = __builtin_amdgcn_mfma_f32_16x16x32_bf16(af, b1, acc1[t], 0, 0, 0);
        }
    }
    if (o0 < O) {
        float bv = (blockIdx.y == 0) ? bias[o0] : 0.f;
#pragma unroll
        for (int t = 0; t < 10; ++t)
#pragma unroll
            for (int r = 0; r < 4; ++r)
                atomicAdd(&Cout[(size_t)(t * 16 + quad * 4 + r) * O + o0], acc0[t][r] + bv);
    }
    if (o1 < O) {
        float bv = (blockIdx.y == 0) ? bias[o1] : 0.f;
#pragma unroll
        for (int t = 0; t < 10; ++t)
#pragma unroll
            for (int r = 0; r < 4; ++r)
                atomicAdd(&Cout[(size_t)(t * 16 + quad * 4 + r) * O + o1], acc1[t][r] + bv);
    }
}

// ------------------------------------ relu + bf16 convert (ff1), S-way fold
__global__ __launch_bounds__(256) void relu_cvt_kernel(const float* __restrict__ in,
                                                       int S, size_t sstr,
                                                       short* __restrict__ out,
                                                       int n) {
    int i = blockIdx.x * 256 + threadIdx.x;
    if (i < n) {
        float v = 0.f;
        for (int s = 0; s < S; ++s) v += in[(size_t)s * sstr + i];
        out[i] = f2bf(fmaxf(v, 0.f));
    }
}

// --------------------- qkv partials -> padded bf16 q/k/v, S-fold + v-pad
// grid B_*96: q<80 -> fold+convert; q>=80 -> zero the v pad row.
__global__ __launch_bounds__(256) void qkv_cvt_kernel(const float* __restrict__ part,
                                                      int S,
                                                      short* __restrict__ q_bf,
                                                      short* __restrict__ k_bf,
                                                      short* __restrict__ v_bf) {
    int mb = blockIdx.x;
    int b = mb / 96, q = mb % 96;
    if (q >= N_) {
        for (int d = threadIdx.x; d < KPD_; d += 256)
            v_bf[((size_t)b * 96 + q) * KPD_ + d] = 0;
        return;
    }
    int m = b * N_ + q;
    for (int d = threadIdx.x; d < KPD_; d += 256) {
        short qv = 0, kv = 0, vv = 0;
        if (d < D_) {
            float qf = 0.f, kf = 0.f, vf = 0.f;
            for (int s = 0; s < S; ++s) {
                const float* p = part + (size_t)s * M_ * QKV_ + (size_t)m * QKV_;
                qf += p[d]; kf += p[D_ + d]; vf += p[2 * D_ + d];
            }
            qv = f2bf(qf); kv = f2bf(kf); vv = f2bf(vf);
        }
        q_bf[(size_t)m * KPD_ + d] = qv;
        k_bf[(size_t)m * KPD_ + d] = kv;
        v_bf[((size_t)b * 96 + q) * KPD_ + d] = vv;
    }
}

// ---------------- fused scores+softmax: grid (b*5+qt) = 10 blocks, 256 thr
// 4 waves split the 97 k-chunks; LDS reduce to 16x80 score tile; in-block
// softmax (16-lane-group shuffle reduce); write p_bf [M_][96] (cols 80+ = 0).
__global__ __launch_bounds__(256) void attn_sc(const short* __restrict__ q_bf,
                                               const short* __restrict__ k_bf,
                                               short* __restrict__ p_bf) {
    int bi = blockIdx.x;
    int b = bi / 5, qt = bi % 5;
    int lane = threadIdx.x & 63, wave = threadIdx.x >> 6;
    int col = lane & 15, quad = lane >> 4;
    const short* qbase = q_bf + (size_t)(b * N_ + qt * 16 + col) * KPD_ + quad * 8;
    const short* kb = k_bf + (size_t)(b * N_ + col) * KPD_ + quad * 8;

    f32x4 acc[5];
#pragma unroll
    for (int kt = 0; kt < 5; ++kt)
#pragma unroll
        for (int r = 0; r < 4; ++r) acc[kt][r] = 0.f;

    int c0 = wave * 25, c1 = min(97, c0 + 25);
    for (int c = c0; c < c1; ++c) {
        bf16x8 af = *(const bf16x8*)(qbase + (size_t)c * 32);
#pragma unroll
        for (int kt = 0; kt < 5; ++kt) {
            bf16x8 kf = *(const bf16x8*)(kb + (size_t)(kt * 16) * KPD_ + (size_t)c * 32);
            acc[kt] = __builtin_amdgcn_mfma_f32_16x16x32_bf16(af, kf, acc[kt], 0, 0, 0);
        }
    }

    __shared__ f32x4 red[4][5][64];      // 20 KB
    __shared__ float sl[16][80];         // 5 KB
#pragma unroll
    for (int kt = 0; kt < 5; ++kt) red[wave][kt][lane] = acc[kt];
    __syncthreads();
    float scale = rsqrtf((float)D_);
    for (int item = threadIdx.x; item < 320; item += 256) {
        int kt = item >> 6, l2 = item & 63;
        int c2 = l2 & 15, q2 = l2 >> 4;
        f32x4 v = red[0][kt][l2];
#pragma unroll
        for (int w = 1; w < 4; ++w)
#pragma unroll
            for (int r = 0; r < 4; ++r) v[r] += red[w][kt][l2][r];
#pragma unroll
        for (int r = 0; r < 4; ++r)
            sl[q2 * 4 + r][kt * 16 + c2] = v[r] * scale;
    }
    __syncthreads();

    // softmax: wave w -> rows w*4 .. w*4+3; 16 lanes per row, 5 cols each
    int r = wave * 4 + (lane >> 4);
    int cb = lane & 15;
    float v[5];
    float mx = -1e30f;
#pragma unroll
    for (int i = 0; i < 5; ++i) { v[i] = sl[r][cb + 16 * i]; mx = fmaxf(mx, v[i]); }
#pragma unroll
    for (int off = 1; off < 16; off <<= 1) mx = fmaxf(mx, __shfl_xor(mx, off, 64));
    float e[5];
    float sum = 0.f;
#pragma unroll
    for (int i = 0; i < 5; ++i) { e[i] = expf(v[i] - mx); sum += e[i]; }
#pragma unroll
    for (int off = 1; off < 16; off <<= 1) sum += __shfl_xor(sum, off, 64);
    float rs = 1.0f / sum;
    size_t m96 = (size_t)(b * N_ + qt * 16 + r) * 96;
#pragma unroll
    for (int i = 0; i < 5; ++i) p_bf[m96 + cb + 16 * i] = f2bf(e[i] * rs);
    p_bf[m96 + 80 + cb] = 0;
}

// ------------------------------------------------ av = P·V via MFMA
__global__ __launch_bounds__(256) void av_mfma(const short* __restrict__ p_bf,
                                               const short* __restrict__ v_bf,
                                               short* __restrict__ av_bf) {
    int bi = blockIdx.x;
    int b = bi / 49, g = bi % 49;
    int lane = threadIdx.x & 63, wave = threadIdx.x >> 6;
    int dtile = g * 4 + wave;
    if (dtile >= 194) return;
    int d0 = dtile * 16;
    int col = lane & 15, quad = lane >> 4;
    const short* pbase = p_bf + (size_t)b * N_ * 96 + quad * 8;
    const short* vb = v_bf + (size_t)b * 96 * KPD_ + d0 + col;
    f32x4 acc[5];
#pragma unroll
    for (int t = 0; t < 5; ++t)
#pragma unroll
        for (int r = 0; r < 4; ++r) acc[t][r] = 0.f;
#pragma unroll
    for (int c = 0; c < 3; ++c) {
        bf16x8 bf8;
#pragma unroll
        for (int j = 0; j < 8; ++j)
            bf8[j] = vb[(size_t)(c * 32 + quad * 8 + j) * KPD_];
#pragma unroll
        for (int t = 0; t < 5; ++t) {
            bf16x8 af = *(const bf16x8*)(pbase + (size_t)(t * 16 + col) * 96 + c * 32);
            acc[t] = __builtin_amdgcn_mfma_f32_16x16x32_bf16(af, bf8, acc[t], 0, 0, 0);
        }
    }
#pragma unroll
    for (int t = 0; t < 5; ++t)
#pragma unroll
        for (int r = 0; r < 4; ++r)
            av_bf[(size_t)(b * N_ + t * 16 + quad * 4 + r) * KPD_ + d0 + col] = f2bf(acc[t][r]);
}

// ------------------------------------------- layernorm, S-way partial fold
template <bool WF32>
__global__ __launch_bounds__(256) void ln_kernel(const float* __restrict__ xin,
                                                 int S, size_t sstr,
                                                 const float* __restrict__ res,
                                                 const float* __restrict__ g,
                                                 const float* __restrict__ bta,
                                                 float* __restrict__ outf,
                                                 short* __restrict__ outb) {
    int m = blockIdx.x;
    int tid = threadIdx.x;
    __shared__ float red[10];
    const float* xr = xin + (size_t)m * D_;
    const float* rr = res + (size_t)m * D_;
    float vv[13];
    float s = 0.f, s2 = 0.f;
#pragma unroll
    for (int i = 0; i < 13; ++i) {
        int d = tid + i * 256;
        float v = 0.f;
        if (d < D_) {
            v = rr[d];
            for (int sp = 0; sp < S; ++sp) v += xr[(size_t)sp * sstr + d];
            s += v; s2 += v * v;
        }
        vv[i] = v;
    }
    block_reduce_2(s, s2, red);
    float mean = s / (float)D_;
    float var = s2 / (float)D_ - mean * mean;
    float inv = rsqrtf(var + EPS_);
#pragma unroll
    for (int i = 0; i < 13; ++i) {
        int d = tid + i * 256;
        if (d < D_) {
            float y = g[d] * (vv[i] - mean) * inv + bta[d];
            if (WF32) outf[(size_t)m * D_ + d] = y;
            outb[(size_t)m * KPD_ + d] = f2bf(y);
        } else if (d < KPD_) {
            outb[(size_t)m * KPD_ + d] = 0;
        }
    }
}

// ---------------------------------------------------------------- update
__global__ __launch_bounds__(256) void update_kernel(const float* __restrict__ part,
                                                     int S, size_t sstr,
                                                     float* __restrict__ curr,
                                                     float* __restrict__ pre_q,
                                                     float* __restrict__ results) {
    int m = blockIdx.x;
    int tid = threadIdx.x;
    const float* pr = part + (size_t)m * OD_;
    for (int c = tid; c < C_; c += 256) {
        float v = 0.f;
        for (int s = 0; s < S; ++s) v += pr[(size_t)s * sstr + c];
        pre_q[(size_t)m * C_ + c] += v;
    }
    if (tid < 2) {
        float v = 0.f;
        for (int s = 0; s < S; ++s) v += pr[(size_t)s * sstr + C_ + tid];
        float nc = curr[m * 2 + tid] + v;
        nc = fminf(fmaxf(nc, 0.f), 223.f);
        curr[m * 2 + tid] = nc;
        results[m * 2 + tid] = nc;
    }
}

// ---------------------------------------------------------------- launch
extern "C" void kernel_launch(void* const* d_in, const int* in_sizes, int n_in,
                              void* d_out, int out_size, void* d_ws, size_t ws_size,
                              hipStream_t stream) {
    const float* pre_f   = (const float*)d_in[0];
    const float* curr_f  = (const float*)d_in[1];
    const float* first_f = (const float*)d_in[2];
    const int*   prev_b  = (const int*)d_in[3];
    const int*   first_b = (const int*)d_in[4];
    const float* ln_g    = (const float*)d_in[5];
    const float* ln_b    = (const float*)d_in[6];
    const float* ipw     = (const float*)d_in[7];
    const float* ipb     = (const float*)d_in[8];
    const float* opw     = (const float*)d_in[9];
    const float* opb     = (const float*)d_in[10];
    const float* n1g     = (const float*)d_in[11];
    const float* n1b     = (const float*)d_in[12];
    const float* l1w     = (const float*)d_in[13];
    const float* l1b     = (const float*)d_in[14];
    const float* l2w     = (const float*)d_in[15];
    const float* l2b     = (const float*)d_in[16];
    const float* n2g     = (const float*)d_in[17];
    const float* n2b     = (const float*)d_in[18];
    const float* ow      = (const float*)d_in[19];
    const float* ob      = (const float*)d_in[20];
    float* outp = (float*)d_out;

    float* wf = (float*)d_ws;
    size_t off = 0;
    // ---- common buffers
    int*   fb_al   = (int*)(wf + off); off += 320;
    float* curr    = wf + off;         off += 320;
    float* pre_q   = wf + off;         off += (size_t)M_ * C_;
    float* first_q = wf + off;         off += (size_t)M_ * C_;
    float* tokens  = wf + off;         off += (size_t)M_ * D_;
    float* xbuf    = wf + off;         off += (size_t)M_ * D_;
    float* pe_tab  = wf + off;         off += (size_t)N_ * D_;
    short* tokens_bf = (short*)(wf + off); off += (size_t)M_ * KPD_ / 2;
    short* x_bf      = (short*)(wf + off); off += (size_t)M_ * KPD_ / 2;
    short* x2_bf     = (short*)(wf + off); off += (size_t)M_ * KPD_ / 2;
    short* av_bf     = (short*)(wf + off); off += (size_t)M_ * KPD_ / 2;
    short* ff1_bf    = (short*)(wf + off); off += (size_t)M_ * DFF_ / 2;
    short* q_bf      = (short*)(wf + off); off += (size_t)M_ * KPD_ / 2;
    short* k_bf      = (short*)(wf + off); off += (size_t)M_ * KPD_ / 2;
    short* v_bf      = (short*)(wf + off); off += (size_t)B_ * 96 * KPD_ / 2;
    short* p_bf      = (short*)(wf + off); off += (size_t)M_ * 96 / 2;
    size_t commonF = off;

    // ---- tier-2: packed weights (strips padded to x16 groups) + partials
    size_t o2 = commonF;
    short* ipw_p2 = (short*)(wf + o2); o2 += (size_t)592 * 97 * 256;
    short* opw_p2 = (short*)(wf + o2); o2 += (size_t)208 * 97 * 256;
    short* l1w_p2 = (short*)(wf + o2); o2 += (size_t)128 * 97 * 256;
    short* l2w_p2 = (short*)(wf + o2); o2 += (size_t)208 * 64 * 256;
    short* ow_p2  = (short*)(wf + o2); o2 += (size_t)80  * 97 * 256;
    float* gpart  = wf + o2;           o2 += (size_t)SQKV * M_ * QKV_;

    // ---- tier-0: fp32 GEMM outs (fallback)
    size_t o0 = commonF;
    float* qkv   = wf + o0; o0 += (size_t)M_ * QKV_;
    float* aout  = wf + o0; o0 += (size_t)M_ * D_;
    float* ff1f  = wf + o0; o0 += (size_t)M_ * DFF_;
    float* ffout = wf + o0; o0 += (size_t)M_ * D_;
    float* outb  = wf + o0; o0 += (size_t)M_ * OD_;

    int tier = (ws_size >= o2 * sizeof(float)) ? 2 : 0;
    (void)in_sizes; (void)n_in; (void)out_size;

    hipLaunchKernelGGL(align_kernel, dim3(B_), dim3(128), 0, stream,
                       prev_b, first_b, fb_al);
    hipLaunchKernelGGL(gather_init_kernel, dim3(M_), dim3(256), 0, stream,
                       pre_f, first_f, prev_b, fb_al, pre_q, first_q, curr);
    hipLaunchKernelGGL(pe_kernel, dim3(N_), dim3(256), 0, stream, pe_tab);

    if (tier == 2) {
        hipLaunchKernelGGL(wpack2, dim3(592 * 97 / 4), dim3(256), 0, stream,
                           ipw, ipw_p2, D_, QKV_, 97, 592 * 97);
        hipLaunchKernelGGL(wpack2, dim3(208 * 97 / 4), dim3(256), 0, stream,
                           opw, opw_p2, D_, D_, 97, 208 * 97);
        hipLaunchKernelGGL(wpack2, dim3(128 * 97 / 4), dim3(256), 0, stream,
                           l1w, l1w_p2, D_, DFF_, 97, 128 * 97);
        hipLaunchKernelGGL(wpack2, dim3(208 * 64 / 4), dim3(256), 0, stream,
                           l2w, l2w_p2, DFF_, D_, 64, 208 * 64);
        hipLaunchKernelGGL(wpack2, dim3(80 * 97 / 4), dim3(256), 0, stream,
                           ow, ow_p2, D_, OD_, 97, 80 * 97);
    }

    for (int it = 0; it < 3; ++it) {
        if (tier == 0) {
            hipMemsetAsync(qkv,   0, (size_t)M_ * QKV_ * 4, stream);
            hipMemsetAsync(aout,  0, (size_t)M_ * D_   * 4, stream);
            hipMemsetAsync(ff1f,  0, (size_t)M_ * DFF_ * 4, stream);
            hipMemsetAsync(ffout, 0, (size_t)M_ * D_   * 4, stream);
            hipMemsetAsync(outb,  0, (size_t)M_ * OD_  * 4, stream);
        }

        hipLaunchKernelGGL(tokens_kernel, dim3(M_), dim3(256), 0, stream,
                           curr_f, pre_q, first_q, curr, ln_g, ln_b, pe_tab,
                           tokens, tokens_bf);
        // ---------------- qkv
        if (tier == 2)
            hipLaunchKernelGGL((gemm_stage<2>), dim3(37, SQKV), dim3(512), 0, stream,
                               tokens_bf, ipw_p2, ipb, gpart, KPD_, 97, QKV_, PQKV);
        else
            hipLaunchKernelGGL(gemm_mfma_sk, dim3(73, 6), dim3(256), 0, stream,
                               tokens_bf, ipw, ipb, qkv, D_, KPD_, QKV_, 544);
        hipLaunchKernelGGL(qkv_cvt_kernel, dim3(B_ * 96), dim3(256), 0, stream,
                           (tier == 2) ? gpart : qkv, (tier == 2) ? SQKV : 1,
                           q_bf, k_bf, v_bf);
        hipLaunchKernelGGL(attn_sc, dim3(B_ * 5), dim3(256), 0, stream,
                           q_bf, k_bf, p_bf);
        hipLaunchKernelGGL(av_mfma, dim3(98), dim3(256), 0, stream,
                           p_bf, v_bf, av_bf);
        // ---------------- out-proj
        if (tier == 2)
            hipLaunchKernelGGL((gemm_stage<2>), dim3(13, SOP), dim3(512), 0, stream,
                               av_bf, opw_p2, opb, gpart, KPD_, 97, D_, POP);
        else
            hipLaunchKernelGGL(gemm_mfma_sk, dim3(25, 10), dim3(256), 0, stream,
                               av_bf, opw, opb, aout, D_, KPD_, D_, 320);
        hipLaunchKernelGGL((ln_kernel<true>), dim3(M_), dim3(256), 0, stream,
                           (tier == 2) ? gpart : aout, (tier == 2) ? SOP : 1, (size_t)M_ * D_,
                           tokens, n1g, n1b, xbuf, x_bf);
        // ---------------- ff1
        if (tier == 2)
            hipLaunchKernelGGL((gemm_stage<2>), dim3(8, SFF1), dim3(512), 0, stream,
                               x_bf, l1w_p2, l1b, gpart, KPD_, 97, DFF_, PFF1);
        else
            hipLaunchKernelGGL(gemm_mfma_sk, dim3(16, 17), dim3(256), 0, stream,
                               x_bf, l1w, l1b, ff1f, D_, KPD_, DFF_, 192);
        hipLaunchKernelGGL(relu_cvt_kernel, dim3((M_ * DFF_ + 255) / 256), dim3(256), 0, stream,
                           (tier == 2) ? gpart : ff1f, (tier == 2) ? SFF1 : 1, (size_t)M_ * DFF_,
                           ff1_bf, M_ * DFF_);
        // ---------------- ff2
        if (tier == 2)
            hipLaunchKernelGGL((gemm_stage<2>), dim3(13, SFF2), dim3(512), 0, stream,
                               ff1_bf, l2w_p2, l2b, gpart, DFF_, 64, D_, PFF2);
        else
            hipLaunchKernelGGL(gemm_mfma_sk, dim3(25, 11), dim3(256), 0, stream,
                               ff1_bf, l2w, l2b, ffout, DFF_, DFF_, D_, 192);
        hipLaunchKernelGGL((ln_kernel<false>), dim3(M_), dim3(256), 0, stream,
                           (tier == 2) ? gpart : ffout, (tier == 2) ? SFF2 : 1, (size_t)M_ * D_,
                           xbuf, n2g, n2b, (float*)nullptr, x2_bf);
        // ---------------- head
        if (tier == 2)
            hipLaunchKernelGGL((gemm_stage<2>), dim3(5, SHD), dim3(512), 0, stream,
                               x2_bf, ow_p2, ob, gpart, KPD_, 97, OD_, PHD);
        else
            hipLaunchKernelGGL(gemm_mfma_sk, dim3(9, 13), dim3(256), 0, stream,
                               x2_bf, ow, ob, outb, D_, KPD_, OD_, 256);
        hipLaunchKernelGGL(update_kernel, dim3(M_), dim3(256), 0, stream,
                           (tier == 2) ? gpart : outb, (tier == 2) ? SHD : 1, (size_t)M_ * OD_,
                           curr, pre_q, outp + (size_t)it * M_ * 2);
    }
}